// Round 11
// baseline (1164.280 us; speedup 1.0000x reference)
//
#include <hip/hip_runtime.h>
#include <math.h>

#define WDIM   512
#define TLEN   512
#define NBATCH 8
#define NHEADS 4
#define DHEAD  128
#define VOCAB  32000
#define NLAY   2
#define FFDIM  2048
#define DFEAT  1024
#define NT     (NBATCH * TLEN)   // 4096 rows
#define QKVW   (3 * WDIM)        // 1536

typedef unsigned short u16;
typedef __attribute__((ext_vector_type(8))) short bf16x8;
typedef __attribute__((ext_vector_type(4))) float f32x4;

__device__ inline u16 f2bf(float f) {
    union { float f; unsigned u; } v; v.f = f;
    unsigned r = v.u + 0x7fffu + ((v.u >> 16) & 1u);
    return (u16)(r >> 16);
}
__device__ inline u16 to_bf(float f) { return f2bf(f); }
__device__ inline u16 to_bf(u16 v)  { return v; }

// ---------------- f32 -> bf16 flat convert ----------------
__global__ __launch_bounds__(256)
void cvt_kernel(const float* __restrict__ s, u16* __restrict__ d, int n)
{
    int i = blockIdx.x * 256 + threadIdx.x;
    if (i < n) d[i] = f2bf(s[i]);
}

// ---------------- concat per-layer QKV bias: [bq;bk;bv] -> (NLAY,1536) ----------------
__global__ __launch_bounds__(256)
void concat_bias_kernel(const float* __restrict__ bq, const float* __restrict__ bk,
                        const float* __restrict__ bv, float* __restrict__ dst)
{
    int i = blockIdx.x * 256 + threadIdx.x;
    if (i >= NLAY * QKVW) return;
    int l = i / QKVW, j = i - l * QKVW;
    float v = (j < WDIM) ? bq[l * WDIM + j]
            : (j < 2 * WDIM) ? bk[l * WDIM + j - WDIM]
            : bv[l * WDIM + j - 2 * WDIM];
    dst[i] = v;
}

// ---------------- tiled transpose + convert: src (K,N) -> dst (N,K) bf16 ----------------
template<typename T>
__global__ __launch_bounds__(256)
void transpose_cvt_kernel(const T* __restrict__ src, int lds_, long ssn, long ssh,
                          u16* __restrict__ dst, int ldd, long dsn, long dsh,
                          int HH)
{
    int z = blockIdx.z;
    int zn = z / HH, zh = z - zn * HH;
    src += (long)zn * ssn + (long)zh * ssh;
    dst += (long)zn * dsn + (long)zh * dsh;
    __shared__ T tile[32][33];
    int n0 = blockIdx.x * 32, k0 = blockIdx.y * 32;
    int tx = threadIdx.x & 31, ty = threadIdx.x >> 5;  // 32 x 8
    #pragma unroll
    for (int i = 0; i < 32; i += 8)
        tile[ty + i][tx] = src[(long)(k0 + ty + i) * lds_ + n0 + tx];
    __syncthreads();
    #pragma unroll
    for (int i = 0; i < 32; i += 8)
        dst[(long)(n0 + ty + i) * ldd + k0 + tx] = to_bf(tile[tx][ty + i]);
}

// ---------------- embed + positional encoding ----------------
__global__ __launch_bounds__(128)
void embed_kernel(const int* __restrict__ captions, const float* __restrict__ emb,
                  const float* __restrict__ pe, float* __restrict__ x, u16* __restrict__ xb)
{
    int r = blockIdx.x;            // 0..NT-1
    int t = r % TLEN;
    int cap = captions[r];
    const float4* e4 = (const float4*)(emb + (long)cap * WDIM);
    const float4* p4 = (const float4*)(pe + (long)t * WDIM);
    float4 a = e4[threadIdx.x], b = p4[threadIdx.x];
    float4 o = make_float4(a.x + b.x, a.y + b.y, a.z + b.z, a.w + b.w);
    ((float4*)(x + (long)r * WDIM))[threadIdx.x] = o;
    ushort4 ob = make_ushort4(f2bf(o.x), f2bf(o.y), f2bf(o.z), f2bf(o.w));
    ((ushort4*)(xb + (long)r * WDIM))[threadIdx.x] = ob;
}

// ---------------- bf16 MFMA GEMM: barrier-free register-fragment pipeline ----------
// C[z] = act(alpha * A[z] @ B[z]^T + bias[zn]); A (M,K) bf16 row-major,
// B stored TRANSPOSED (N,K) bf16 row-major -> BOTH operands' MFMA fragments are
// directly per-lane loadable from global (16B aligned dwordx4). No LDS staging,
// no barriers, no waitcnt games: each wave is an independent pipeline with a
// 1-step register ping-pong prefetch; latency hidden by prefetch + wave TLP.
// Race-free by construction. Epilogue LDS (NT path) is separate.
#define GBM 128
#define GBN 128
#define GBK 32

template<int RELU, int NTST, int CAUSAL>
__global__ __launch_bounds__(256)
void mfma_gemm_kernel(const u16* __restrict__ A, int lda, long sAn, long sAh,
                      const u16* __restrict__ B, int ldb, long sBn, long sBh,
                      float* __restrict__ C, u16* __restrict__ Cb, int ldc, long sCn, long sCh,
                      const float* __restrict__ bias, long sbias,
                      int M, int N, int K, int HH, float alpha)
{
    int z = blockIdx.z;
    int zn = z / HH, zh = z - zn * HH;
    A += (long)zn * sAn + (long)zh * sAh;
    B += (long)zn * sBn + (long)zh * sBh;
    long coff = (long)zn * sCn + (long)zh * sCh;
    if (bias) bias += (long)zn * sbias;

    // XCD-chunked bijective swizzle (m204)
    int nwg  = gridDim.x * gridDim.y;
    int orig = blockIdx.y * gridDim.x + blockIdx.x;
    int q = nwg >> 3, r = nwg & 7, xcd = orig & 7, rest = orig >> 3;
    int nw = (xcd < r ? xcd * (q + 1) : r * (q + 1) + (xcd - r) * q) + rest;
    int bx = nw / gridDim.y, by = nw - bx * gridDim.y;
    int bm = by * GBM, bn = bx * GBN;

    if (CAUSAL && bn >= bm + GBM) return;   // fully-masked tile (block-uniform exit)

    __shared__ float ls[32 * 128];     // epilogue staging only (NT path), 16 KB

    int tid = threadIdx.x;
    int w = tid >> 6, lane = tid & 63;
    int wr = w >> 1, wc = w & 1;         // 2x2 wave grid, 64x64 per wave
    int lrow = lane & 15, kgrp = lane >> 4;
    int ko = kgrp * 8;

    // per-lane row base pointers (fragment rows; clamped for ragged M=8)
    const u16* Arow[4];
    const u16* Brow[4];
    #pragma unroll
    for (int m = 0; m < 4; m++) {
        int gr = bm + wr * 64 + m * 16 + lrow; if (gr >= M) gr = M - 1;
        Arow[m] = A + (long)gr * lda;
    }
    #pragma unroll
    for (int n = 0; n < 4; n++)
        Brow[n] = B + (long)(bn + wc * 64 + n * 16 + lrow) * ldb;

    f32x4 acc[4][4] = {};
    int nsteps = K / GBK;

    bf16x8 a0[4], b0[4], a1[4], b1[4];

    auto LOAD = [&](int ks, bf16x8* av, bf16x8* bv) {
        int k0 = ks * GBK + ko;
        #pragma unroll
        for (int m = 0; m < 4; m++) av[m] = *(const bf16x8*)(Arow[m] + k0);
        #pragma unroll
        for (int n = 0; n < 4; n++) bv[n] = *(const bf16x8*)(Brow[n] + k0);
    };
    auto MF = [&](bf16x8* av, bf16x8* bv) {
        #pragma unroll
        for (int m = 0; m < 4; m++)
            #pragma unroll
            for (int n = 0; n < 4; n++)
                acc[m][n] = __builtin_amdgcn_mfma_f32_16x16x32_bf16(av[m], bv[n], acc[m][n], 0, 0, 0);
    };

    LOAD(0, a0, b0);
    for (int ks = 0; ks < nsteps; ks += 2) {
        if (ks + 1 < nsteps) LOAD(ks + 1, a1, b1);   // prefetch under MF(a0)
        MF(a0, b0);
        if (ks + 2 < nsteps) LOAD(ks + 2, a0, b0);   // prefetch under MF(a1)
        if (ks + 1 < nsteps) MF(a1, b1);
    }

    // C/D layout: col = lane&15, row = (lane>>4)*4 + reg   [m89/m91 verified]
    if (NTST) {
        // LDS-staged coalesced NT epilogue: 4 passes of 32 rows x 128 cols f32.
        C += coff;
        #pragma unroll
        for (int pass = 0; pass < 4; pass++) {
            if (wr == (pass >> 1)) {
                #pragma unroll
                for (int m2 = 0; m2 < 2; m2++) {
                    int m = (pass & 1) * 2 + m2;
                    #pragma unroll
                    for (int n = 0; n < 4; n++) {
                        int gc = wc * 64 + n * 16 + lrow;
                        float bvv = bias ? bias[bn + gc] : 0.f;
                        #pragma unroll
                        for (int r2 = 0; r2 < 4; r2++) {
                            float v2 = acc[m][n][r2] * alpha + bvv;
                            if (RELU) v2 = fmaxf(v2, 0.f);
                            ls[(m2 * 16 + kgrp * 4 + r2) * 128 + gc] = v2;
                        }
                    }
                }
            }
            __syncthreads();
            #pragma unroll
            for (int i = 0; i < 4; i++) {
                int j = tid + i * 256;            // 0..1023 f32x4
                int row = j >> 5, cg = j & 31;
                int gr = bm + pass * 32 + row;
                if (gr < M) {
                    f32x4 v4 = *(const f32x4*)&ls[row * 128 + cg * 4];
                    __builtin_nontemporal_store(v4, (f32x4*)&C[(long)gr * ldc + bn + cg * 4]);
                }
            }
            __syncthreads();
        }
        return;
    }

    if (C)  C  += coff;
    if (Cb) Cb += coff;
    #pragma unroll
    for (int m = 0; m < 4; m++) {
        int rb = bm + wr * 64 + m * 16 + kgrp * 4;
        #pragma unroll
        for (int n = 0; n < 4; n++) {
            int gc = bn + wc * 64 + n * 16 + lrow;
            float bvv = bias ? bias[gc] : 0.f;
            #pragma unroll
            for (int r2 = 0; r2 < 4; r2++) {
                int gr = rb + r2;
                if (gr < M) {
                    float v2 = acc[m][n][r2] * alpha + bvv;
                    if (RELU) v2 = fmaxf(v2, 0.f);
                    if (C)  C[(long)gr * ldc + gc]  = v2;
                    if (Cb) Cb[(long)gr * ldc + gc] = f2bf(v2);
                }
            }
        }
    }
}

// ---------------- causal softmax: f32 scores -> bf16 P ----------------
__global__ __launch_bounds__(256)
void softmax_causal_kernel(const float* __restrict__ scores, u16* __restrict__ pb)
{
    long row = blockIdx.x;                 // n*H*T + h*T + s
    int s = (int)(row % TLEN);
    const float* p = scores + row * TLEN;
    u16* o = pb + row * TLEN;
    int tid = threadIdx.x;
    float v0 = p[tid], v1 = p[tid + 256];
    bool m0 = (tid <= s), m1 = (tid + 256 <= s);
    __shared__ float red[256];
    float mx = fmaxf(m0 ? v0 : -INFINITY, m1 ? v1 : -INFINITY);
    red[tid] = mx; __syncthreads();
    for (int off = 128; off > 0; off >>= 1) {
        if (tid < off) red[tid] = fmaxf(red[tid], red[tid + off]);
        __syncthreads();
    }
    mx = red[0]; __syncthreads();
    float e0 = m0 ? expf(v0 - mx) : 0.f;
    float e1 = m1 ? expf(v1 - mx) : 0.f;
    red[tid] = e0 + e1; __syncthreads();
    for (int off = 128; off > 0; off >>= 1) {
        if (tid < off) red[tid] += red[tid + off];
        __syncthreads();
    }
    float inv = 1.f / red[0];
    o[tid]       = f2bf(e0 * inv);
    o[tid + 256] = f2bf(e1 * inv);
}

// ---------------- generic row reduce+normalize helper (in-kernel) ----------------
__device__ inline void ln_pass(float& v0, float& v1, const float* __restrict__ w,
                               const float* __restrict__ b, float* red, int tid)
{
    red[tid] = v0 + v1; __syncthreads();
    for (int off = 128; off > 0; off >>= 1) {
        if (tid < off) red[tid] += red[tid + off];
        __syncthreads();
    }
    float mean = red[0] * (1.f / WDIM); __syncthreads();
    float d0 = v0 - mean, d1 = v1 - mean;
    red[tid] = d0 * d0 + d1 * d1; __syncthreads();
    for (int off = 128; off > 0; off >>= 1) {
        if (tid < off) red[tid] += red[tid + off];
        __syncthreads();
    }
    float rstd = 1.f / sqrtf(red[0] * (1.f / WDIM) + 1e-5f);
    __syncthreads();
    v0 = d0 * rstd * w[tid] + b[tid];
    v1 = d1 * rstd * w[tid + 256] + b[tid + 256];
}

// ---------------- x = LayerNorm(x + t2); writes f32 x and bf16 xb ----------------
__global__ __launch_bounds__(256)
void add_ln_kernel(float* __restrict__ x, u16* __restrict__ xb,
                   const float* __restrict__ t2,
                   const float* __restrict__ w, const float* __restrict__ b)
{
    long r = blockIdx.x;
    float* xr = x + r * WDIM;
    u16* xbr = xb + r * WDIM;
    const float* tr = t2 + r * WDIM;
    int tid = threadIdx.x;
    float v0 = xr[tid] + tr[tid];
    float v1 = xr[tid + 256] + tr[tid + 256];
    __shared__ float red[256];
    ln_pass(v0, v1, w, b, red, tid);
    xr[tid] = v0;        xr[tid + 256] = v1;
    xbr[tid] = f2bf(v0); xbr[tid + 256] = f2bf(v1);
}

// ---------------- fused: x = LN2(LN1(x + t2) + cav[batch]) ----------------
__global__ __launch_bounds__(256)
void add_ln2_kernel(float* __restrict__ x, u16* __restrict__ xb,
                    const float* __restrict__ t2, const float* __restrict__ cav,
                    const float* __restrict__ w1, const float* __restrict__ b1,
                    const float* __restrict__ w2, const float* __restrict__ b2)
{
    long r = blockIdx.x;
    float* xr = x + r * WDIM;
    u16* xbr = xb + r * WDIM;
    const float* tr = t2 + r * WDIM;
    const float* cr = cav + (r / TLEN) * WDIM;   // per-batch broadcast row
    int tid = threadIdx.x;
    float v0 = xr[tid] + tr[tid];
    float v1 = xr[tid + 256] + tr[tid + 256];
    __shared__ float red[256];
    ln_pass(v0, v1, w1, b1, red, tid);
    __syncthreads();
    v0 += cr[tid]; v1 += cr[tid + 256];
    ln_pass(v0, v1, w2, b2, red, tid);
    xr[tid] = v0;        xr[tid + 256] = v1;
    xbr[tid] = f2bf(v0); xbr[tid + 256] = f2bf(v1);
}

extern "C" void kernel_launch(void* const* d_in, const int* in_sizes, int n_in,
                              void* d_out, int out_size, void* d_ws, size_t ws_size,
                              hipStream_t stream)
{
    const float* features = (const float*)d_in[0];
    const int*   captions = (const int*)  d_in[1];
    const float* emb      = (const float*)d_in[2];
    const float* pe       = (const float*)d_in[3];
    const float* vis_w    = (const float*)d_in[4];
    const float* vis_b    = (const float*)d_in[5];
    const float* sa_wq    = (const float*)d_in[6];
    const float* sa_bq    = (const float*)d_in[7];
    const float* sa_wk    = (const float*)d_in[8];
    const float* sa_bk    = (const float*)d_in[9];
    const float* sa_wv    = (const float*)d_in[10];
    const float* sa_bv    = (const float*)d_in[11];
    const float* sa_wo    = (const float*)d_in[12];
    const float* sa_bo    = (const float*)d_in[13];
    // ca_wq/bq/wk/bk (14..17) unused: len-1 memory => softmax == 1 identically
    const float* ca_wv    = (const float*)d_in[18];
    const float* ca_bv    = (const float*)d_in[19];
    const float* ca_wo    = (const float*)d_in[20];
    const float* ca_bo    = (const float*)d_in[21];
    const float* ff1_w    = (const float*)d_in[22];
    const float* ff1_b    = (const float*)d_in[23];
    const float* ff2_w    = (const float*)d_in[24];
    const float* ff2_b    = (const float*)d_in[25];
    const float* ln1_w    = (const float*)d_in[26];
    const float* ln1_b    = (const float*)d_in[27];
    const float* ln2_w    = (const float*)d_in[28];
    const float* ln2_b    = (const float*)d_in[29];
    const float* ln3_w    = (const float*)d_in[30];
    const float* ln3_b    = (const float*)d_in[31];
    const float* out_w    = (const float*)d_in[32];
    const float* out_b    = (const float*)d_in[33];

    // ---- workspace carve ----
    char* p = (char*)d_ws;
    auto alloc = [&](size_t bytes) { char* r = p; p += (bytes + 255) & ~(size_t)255; return r; };
    float* x    = (float*)alloc((size_t)NT * WDIM * 4);
    float* t2   = (float*)alloc((size_t)NT * WDIM * 4);
    float* memb = (float*)alloc((size_t)NBATCH * WDIM * 4);
    float* cav  = (float*)alloc((size_t)NLAY * NBATCH * WDIM * 4);
    // union region: scores f32 (SA phase) | yb bf16 (PV->Oproj) | hb bf16 (FFN)
    char*  reg1 = alloc((size_t)NBATCH * NHEADS * TLEN * TLEN * 4);
    float* scores = (float*)reg1;
    u16*   yb     = (u16*)reg1;
    u16*   hb     = (u16*)reg1;
    u16* xb    = (u16*)alloc((size_t)NT * WDIM * 2);
    u16* qkvb  = (u16*)alloc((size_t)NT * QKVW * 2);
    u16* vtb   = (u16*)alloc((size_t)NT * WDIM * 2);
    u16* pb    = (u16*)alloc((size_t)NBATCH * NHEADS * TLEN * TLEN * 2);
    u16* featb = (u16*)alloc((size_t)NBATCH * DFEAT * 2);
    u16* membf = (u16*)alloc((size_t)NBATCH * WDIM * 2);
    u16* cvb   = (u16*)alloc((size_t)NLAY * NBATCH * WDIM * 2);
    float* qkv_bias = (float*)alloc((size_t)NLAY * QKVW * 4);
    u16* vis_wT = (u16*)alloc((size_t)WDIM * DFEAT * 2);
    u16* qkvT   = (u16*)alloc((size_t)NLAY * QKVW * WDIM * 2);
    u16* sa_woT = (u16*)alloc((size_t)NLAY * WDIM * WDIM * 2);
    u16* ca_wvT = (u16*)alloc((size_t)NLAY * WDIM * WDIM * 2);
    u16* ca_woT = (u16*)alloc((size_t)NLAY * WDIM * WDIM * 2);
    u16* ff1T   = (u16*)alloc((size_t)NLAY * WDIM * FFDIM * 2);
    u16* ff2T   = (u16*)alloc((size_t)NLAY * FFDIM * WDIM * 2);
    u16* out_wT = (u16*)alloc((size_t)WDIM * VOCAB * 2);

    auto gemm = [&](const u16* A, int lda, long sAn, long sAh,
                    const u16* B, int ldb, long sBn, long sBh,
                    float* C, u16* Cb, int ldc, long sCn, long sCh,
                    const float* bias, long sbias, int M, int N, int K, int HH, int batch,
                    float alpha, int mode)   // 0=plain 1=relu 2=nt 3=causal
    {
        dim3 g(N / GBN, (M + GBM - 1) / GBM, batch), blk(256);
        if (mode == 2)
            mfma_gemm_kernel<0, 1, 0><<<g, blk, 0, stream>>>(A, lda, sAn, sAh, B, ldb, sBn, sBh,
                                                             C, Cb, ldc, sCn, sCh, bias, sbias, M, N, K, HH, alpha);
        else if (mode == 1)
            mfma_gemm_kernel<1, 0, 0><<<g, blk, 0, stream>>>(A, lda, sAn, sAh, B, ldb, sBn, sBh,
                                                             C, Cb, ldc, sCn, sCh, bias, sbias, M, N, K, HH, alpha);
        else if (mode == 3)
            mfma_gemm_kernel<0, 0, 1><<<g, blk, 0, stream>>>(A, lda, sAn, sAh, B, ldb, sBn, sBh,
                                                             C, Cb, ldc, sCn, sCh, bias, sbias, M, N, K, HH, alpha);
        else
            mfma_gemm_kernel<0, 0, 0><<<g, blk, 0, stream>>>(A, lda, sAn, sAh, B, ldb, sBn, sBh,
                                                             C, Cb, ldc, sCn, sCh, bias, sbias, M, N, K, HH, alpha);
    };
    auto transposeF = [&](const float* src, int lds_, long ssn, long ssh,
                          u16* dst, int ldd, long dsn, long dsh,
                          int K, int N, int batch, int HH)
    {
        dim3 g(N / 32, K / 32, batch), blk(256);
        transpose_cvt_kernel<float><<<g, blk, 0, stream>>>(src, lds_, ssn, ssh, dst, ldd, dsn, dsh, HH);
    };
    auto transposeB = [&](const u16* src, int lds_, long ssn, long ssh,
                          u16* dst, int ldd, long dsn, long dsh,
                          int K, int N, int batch, int HH)
    {
        dim3 g(N / 32, K / 32, batch), blk(256);
        transpose_cvt_kernel<u16><<<g, blk, 0, stream>>>(src, lds_, ssn, ssh, dst, ldd, dsn, dsh, HH);
    };

    // ---- weight conversion (per call; deterministic) ----
    cvt_kernel<<<(NBATCH * DFEAT + 255) / 256, 256, 0, stream>>>(features, featb, NBATCH * DFEAT);
    concat_bias_kernel<<<(NLAY * QKVW + 255) / 256, 256, 0, stream>>>(sa_bq, sa_bk, sa_bv, qkv_bias);
    transposeF(vis_w, WDIM, 0, 0, vis_wT, DFEAT, 0, 0, DFEAT, WDIM, 1, 1);
    transposeF(sa_wq, WDIM, (long)WDIM * WDIM, 0, qkvT,                WDIM, (long)QKVW * WDIM, 0, WDIM, WDIM, NLAY, 1);
    transposeF(sa_wk, WDIM, (long)WDIM * WDIM, 0, qkvT + (long)WDIM * WDIM,     WDIM, (long)QKVW * WDIM, 0, WDIM, WDIM, NLAY, 1);
    transposeF(sa_wv, WDIM, (long)WDIM * WDIM, 0, qkvT + (long)2 * WDIM * WDIM, WDIM, (long)QKVW * WDIM, 0, WDIM, WDIM, NLAY, 1);
    transposeF(sa_wo, WDIM, (long)WDIM * WDIM, 0, sa_woT, WDIM, (long)WDIM * WDIM, 0, WDIM, WDIM, NLAY, 1);
    transposeF(ca_wv, WDIM, (long)WDIM * WDIM, 0, ca_wvT, WDIM, (long)WDIM * WDIM, 0, WDIM, WDIM, NLAY, 1);
    transposeF(ca_wo, WDIM, (long)WDIM * WDIM, 0, ca_woT, WDIM, (long)WDIM * WDIM, 0, WDIM, WDIM, NLAY, 1);
    transposeF(ff1_w, FFDIM, (long)WDIM * FFDIM, 0, ff1T, WDIM, (long)FFDIM * WDIM, 0, WDIM, FFDIM, NLAY, 1);
    transposeF(ff2_w, WDIM, (long)FFDIM * WDIM, 0, ff2T, FFDIM, (long)WDIM * FFDIM, 0, FFDIM, WDIM, NLAY, 1);
    transposeF(out_w, VOCAB, 0, 0, out_wT, WDIM, 0, 0, WDIM, VOCAB, 1, 1);

    // memory = features @ vis_w + vis_b   (8 x 512), keep f32 + bf16
    gemm(featb, DFEAT, 0, 0, vis_wT, DFEAT, 0, 0, memb, membf, WDIM, 0, 0,
         vis_b, 0, NBATCH, WDIM, DFEAT, 1, 1, 1.f, 0);
    // x = emb[captions] + pe
    embed_kernel<<<NT, 128, 0, stream>>>(captions, emb, pe, x, xb);

    // ---- cross-attention, layer-batched (len-1 memory => softmax == 1) ----
    gemm(membf, WDIM, 0, 0, ca_wvT, WDIM, (long)WDIM * WDIM, 0,
         nullptr, cvb, WDIM, (long)NBATCH * WDIM, 0,
         ca_bv, WDIM, NBATCH, WDIM, WDIM, 1, NLAY, 1.f, 0);
    gemm(cvb, WDIM, (long)NBATCH * WDIM, 0, ca_woT, WDIM, (long)WDIM * WDIM, 0,
         cav, nullptr, WDIM, (long)NBATCH * WDIM, 0,
         ca_bo, WDIM, NBATCH, WDIM, WDIM, 1, NLAY, 1.f, 0);

    const float iscale = 1.f / sqrtf((float)DHEAD);
    const long TQ = (long)TLEN * QKVW;
    const long TW = (long)TLEN * WDIM;
    const long TT = (long)TLEN * TLEN;
    for (int l = 0; l < NLAY; l++) {
        long wo  = (long)l * WDIM * WDIM;
        long bo_ = (long)l * WDIM;
        // ---- self-attention: fused QKV projection (N=1536) ----
        gemm(xb, WDIM, 0, 0, qkvT + (long)l * QKVW * WDIM, WDIM, 0, 0,
             nullptr, qkvb, QKVW, 0, 0, qkv_bias + (long)l * QKVW, 0,
             NT, QKVW, WDIM, 1, 1, 1.f, 0);
        // V^T per (n,h): qkvb[n*T+t][1024 + h*128 + d] -> vtb [n][h][d][t]
        transposeB(qkvb + 2 * WDIM, QKVW, TQ, DHEAD,
                   vtb, TLEN, (long)NHEADS * DHEAD * TLEN, (long)DHEAD * TLEN,
                   TLEN, DHEAD, NBATCH * NHEADS, NHEADS);
        // scores = (Q_h @ K_h^T) * iscale  (causal: skip fully-masked tiles)
        gemm(qkvb, QKVW, TQ, DHEAD, qkvb + WDIM, QKVW, TQ, DHEAD,
             scores, nullptr, TLEN, (long)NHEADS * TT, TT,
             nullptr, 0, TLEN, TLEN, DHEAD, NHEADS, NBATCH * NHEADS, iscale, 3);
        softmax_causal_kernel<<<NBATCH * NHEADS * TLEN, 256, 0, stream>>>(scores, pb);
        // y = P @ V_h  (B = V^T tile, (N=d, K=t))
        gemm(pb, TLEN, (long)NHEADS * TT, TT,
             vtb, TLEN, (long)NHEADS * DHEAD * TLEN, (long)DHEAD * TLEN,
             nullptr, yb, WDIM, TW, DHEAD,
             nullptr, 0, TLEN, DHEAD, TLEN, NHEADS, NBATCH * NHEADS, 1.f, 0);
        // t2 = y @ wo + bo
        gemm(yb, WDIM, 0, 0, sa_woT + wo, WDIM, 0, 0, t2, nullptr, WDIM, 0, 0,
             sa_bo + bo_, 0, NT, WDIM, WDIM, 1, 1, 1.f, 0);
        // fused: x = LN2(LN1(x + t2) + cav[l])
        add_ln2_kernel<<<NT, 256, 0, stream>>>(x, xb, t2, cav + (long)l * NBATCH * WDIM,
                                               ln1_w + bo_, ln1_b + bo_, ln2_w + bo_, ln2_b + bo_);
        // ---- FFN ----
        gemm(xb, WDIM, 0, 0, ff1T + (long)l * FFDIM * WDIM, WDIM, 0, 0,
             nullptr, hb, FFDIM, 0, 0, ff1_b + (long)l * FFDIM, 0,
             NT, FFDIM, WDIM, 1, 1, 1.f, 1);
        gemm(hb, FFDIM, 0, 0, ff2T + (long)l * WDIM * FFDIM, FFDIM, 0, 0,
             t2, nullptr, WDIM, 0, 0, ff2_b + bo_, 0, NT, WDIM, FFDIM, 1, 1, 1.f, 0);
        add_ln_kernel<<<NT, 256, 0, stream>>>(x, xb, t2, ln3_w + bo_, ln3_b + bo_);
    }
    // out = x @ out_w + out_b   (4096 x 32000) — coalesced non-temporal f32 stores
    gemm(xb, WDIM, 0, 0, out_wT, WDIM, 0, 0, (float*)d_out, nullptr, VOCAB, 0, 0,
         out_b, 0, NT, VOCAB, WDIM, 1, 1, 1.f, 2);
}

// Round 12
// 732.132 us; speedup vs baseline: 1.5903x; 1.5903x over previous
//
#include <hip/hip_runtime.h>
#include <math.h>

#define WDIM   512
#define TLEN   512
#define NBATCH 8
#define NHEADS 4
#define DHEAD  128
#define VOCAB  32000
#define NLAY   2
#define FFDIM  2048
#define DFEAT  1024
#define NT     (NBATCH * TLEN)   // 4096 rows
#define QKVW   (3 * WDIM)        // 1536

typedef unsigned short u16;
typedef __attribute__((ext_vector_type(8))) short bf16x8;
typedef __attribute__((ext_vector_type(4))) float f32x4;

__device__ inline u16 f2bf(float f) {
    union { float f; unsigned u; } v; v.f = f;
    unsigned r = v.u + 0x7fffu + ((v.u >> 16) & 1u);
    return (u16)(r >> 16);
}
__device__ inline u16 to_bf(float f) { return f2bf(f); }
__device__ inline u16 to_bf(u16 v)  { return v; }

// ---------------- f32 -> bf16 flat convert ----------------
__global__ __launch_bounds__(256)
void cvt_kernel(const float* __restrict__ s, u16* __restrict__ d, int n)
{
    int i = blockIdx.x * 256 + threadIdx.x;
    if (i < n) d[i] = f2bf(s[i]);
}

// ---------------- concat per-layer QKV bias: [bq;bk;bv] -> (NLAY,1536) ----------------
__global__ __launch_bounds__(256)
void concat_bias_kernel(const float* __restrict__ bq, const float* __restrict__ bk,
                        const float* __restrict__ bv, float* __restrict__ dst)
{
    int i = blockIdx.x * 256 + threadIdx.x;
    if (i >= NLAY * QKVW) return;
    int l = i / QKVW, j = i - l * QKVW;
    float v = (j < WDIM) ? bq[l * WDIM + j]
            : (j < 2 * WDIM) ? bk[l * WDIM + j - WDIM]
            : bv[l * WDIM + j - 2 * WDIM];
    dst[i] = v;
}

// ---------------- tiled transpose + convert: src (K,N) -> dst (N,K) bf16 ----------------
template<typename T>
__global__ __launch_bounds__(256)
void transpose_cvt_kernel(const T* __restrict__ src, int lds_, long ssn, long ssh,
                          u16* __restrict__ dst, int ldd, long dsn, long dsh,
                          int HH)
{
    int z = blockIdx.z;
    int zn = z / HH, zh = z - zn * HH;
    src += (long)zn * ssn + (long)zh * ssh;
    dst += (long)zn * dsn + (long)zh * dsh;
    __shared__ T tile[32][33];
    int n0 = blockIdx.x * 32, k0 = blockIdx.y * 32;
    int tx = threadIdx.x & 31, ty = threadIdx.x >> 5;  // 32 x 8
    #pragma unroll
    for (int i = 0; i < 32; i += 8)
        tile[ty + i][tx] = src[(long)(k0 + ty + i) * lds_ + n0 + tx];
    __syncthreads();
    #pragma unroll
    for (int i = 0; i < 32; i += 8)
        dst[(long)(n0 + ty + i) * ldd + k0 + tx] = to_bf(tile[tx][ty + i]);
}

// ---------------- embed + positional encoding ----------------
__global__ __launch_bounds__(128)
void embed_kernel(const int* __restrict__ captions, const float* __restrict__ emb,
                  const float* __restrict__ pe, float* __restrict__ x, u16* __restrict__ xb)
{
    int r = blockIdx.x;            // 0..NT-1
    int t = r % TLEN;
    int cap = captions[r];
    const float4* e4 = (const float4*)(emb + (long)cap * WDIM);
    const float4* p4 = (const float4*)(pe + (long)t * WDIM);
    float4 a = e4[threadIdx.x], b = p4[threadIdx.x];
    float4 o = make_float4(a.x + b.x, a.y + b.y, a.z + b.z, a.w + b.w);
    ((float4*)(x + (long)r * WDIM))[threadIdx.x] = o;
    ushort4 ob = make_ushort4(f2bf(o.x), f2bf(o.y), f2bf(o.z), f2bf(o.w));
    ((ushort4*)(xb + (long)r * WDIM))[threadIdx.x] = ob;
}

// ---------------- bf16 MFMA GEMM: 2-deep counted-vmcnt pipeline (round-8/10 proven) --
// C[z] = act(alpha * A[z] @ B[z]^T + bias[zn]); A (M,K) bf16 row-major,
// B stored TRANSPOSED (N,K) bf16 row-major. C f32 and/or Cb bf16 outputs.
// Per K-step: STAGE(next) -> s_waitcnt vmcnt(4) -> s_barrier -> ds_read+MFMA
// -> s_barrier. sched_barrier(0) fences pin memory ops to their phase.
#define GBM 128
#define GBN 128
#define GBK 32

template<int RELU, int NTST, int CAUSAL>
__global__ __launch_bounds__(256)
void mfma_gemm_kernel(const u16* __restrict__ A, int lda, long sAn, long sAh,
                      const u16* __restrict__ B, int ldb, long sBn, long sBh,
                      float* __restrict__ C, u16* __restrict__ Cb, int ldc, long sCn, long sCh,
                      const float* __restrict__ bias, long sbias,
                      int M, int N, int K, int HH, float alpha)
{
    int z = blockIdx.z;
    int zn = z / HH, zh = z - zn * HH;
    A += (long)zn * sAn + (long)zh * sAh;
    B += (long)zn * sBn + (long)zh * sBh;
    long coff = (long)zn * sCn + (long)zh * sCh;
    if (bias) bias += (long)zn * sbias;

    // XCD-chunked bijective swizzle (m204)
    int nwg  = gridDim.x * gridDim.y;
    int orig = blockIdx.y * gridDim.x + blockIdx.x;
    int q = nwg >> 3, r = nwg & 7, xcd = orig & 7, rest = orig >> 3;
    int nw = (xcd < r ? xcd * (q + 1) : r * (q + 1) + (xcd - r) * q) + rest;
    int bx = nw / gridDim.y, by = nw - bx * gridDim.y;
    int bm = by * GBM, bn = bx * GBN;

    if (CAUSAL && bn >= bm + GBM) return;   // fully-masked tile (block-uniform exit)

    __shared__ u16 As[2][GBM * GBK];   // [buf][row*GBK + k], k contiguous
    __shared__ u16 Bs[2][GBN * GBK];

    int tid = threadIdx.x;
    int w = tid >> 6, lane = tid & 63;
    int wr = w >> 1, wc = w & 1;         // 2x2 wave grid, 64x64 per wave
    int lrow = lane & 15, kgrp = lane >> 4;

    int c0row = tid >> 2, c0ko = (tid & 3) << 3;
    long ldsOff = (size_t)(w * 64) * 8;

    auto STAGE = [&](int buf, int ks) {    // 4 global_load_lds per wave
        int k0 = ks * GBK;
        #pragma unroll
        for (int i = 0; i < 2; i++) {
            int row = c0row + i * 64;
            int gr = bm + row; if (gr >= M) gr = M - 1;   // clamp (ragged M=8)
            const u16* srcA = A + (long)gr * lda + k0 + c0ko;
            u16* dstA = &As[buf][ldsOff + (size_t)i * 256 * 8];
            __builtin_amdgcn_global_load_lds((const __attribute__((address_space(1))) void*)srcA,
                                             (__attribute__((address_space(3))) void*)dstA, 16, 0, 0);
            const u16* srcB = B + (long)(bn + row) * ldb + k0 + c0ko;
            u16* dstB = &Bs[buf][ldsOff + (size_t)i * 256 * 8];
            __builtin_amdgcn_global_load_lds((const __attribute__((address_space(1))) void*)srcB,
                                             (__attribute__((address_space(3))) void*)dstB, 16, 0, 0);
        }
    };

    f32x4 acc[4][4] = {};
    int nsteps = K / GBK;

    STAGE(0, 0);     // 4 loads in flight

    for (int ks = 0; ks < nsteps; ks++) {
        int cur = ks & 1;
        if (ks + 1 < nsteps) {
            STAGE(cur ^ 1, ks + 1);                       // 4 more in flight (8 total)
            asm volatile("s_waitcnt vmcnt(4)" ::: "memory");   // cur's 4 done; next's fly
        } else {
            asm volatile("s_waitcnt vmcnt(0)" ::: "memory");   // final: drain
        }
        __builtin_amdgcn_sched_barrier(0);
        __builtin_amdgcn_s_barrier();                     // all waves' cur quarters visible
        __builtin_amdgcn_sched_barrier(0);
        bf16x8 av[4], bv[4];
        #pragma unroll
        for (int m = 0; m < 4; m++)
            av[m] = *(const bf16x8*)&As[cur][(wr * 64 + m * 16 + lrow) * GBK + kgrp * 8];
        #pragma unroll
        for (int n = 0; n < 4; n++)
            bv[n] = *(const bf16x8*)&Bs[cur][(wc * 64 + n * 16 + lrow) * GBK + kgrp * 8];
        #pragma unroll
        for (int m = 0; m < 4; m++)
            #pragma unroll
            for (int n = 0; n < 4; n++)
                acc[m][n] = __builtin_amdgcn_mfma_f32_16x16x32_bf16(av[m], bv[n], acc[m][n], 0, 0, 0);
        __builtin_amdgcn_sched_barrier(0);
        __builtin_amdgcn_s_barrier();                     // reads of cur done -> safe overwrite
        __builtin_amdgcn_sched_barrier(0);
    }

    // C/D layout: col = lane&15, row = (lane>>4)*4 + reg   [m89/m91 verified]
    if (NTST) {
        __syncthreads();                  // full drain before LDS reuse
        float* ls = (float*)&As[0][0];     // 32*128 f32 = 16 KB
        C += coff;
        #pragma unroll
        for (int pass = 0; pass < 4; pass++) {
            if (wr == (pass >> 1)) {
                #pragma unroll
                for (int m2 = 0; m2 < 2; m2++) {
                    int m = (pass & 1) * 2 + m2;
                    #pragma unroll
                    for (int n = 0; n < 4; n++) {
                        int gc = wc * 64 + n * 16 + lrow;
                        float bvv = bias ? bias[bn + gc] : 0.f;
                        #pragma unroll
                        for (int r2 = 0; r2 < 4; r2++) {
                            float v2 = acc[m][n][r2] * alpha + bvv;
                            if (RELU) v2 = fmaxf(v2, 0.f);
                            ls[(m2 * 16 + kgrp * 4 + r2) * 128 + gc] = v2;
                        }
                    }
                }
            }
            __syncthreads();
            #pragma unroll
            for (int i = 0; i < 4; i++) {
                int j = tid + i * 256;            // 0..1023 f32x4
                int row = j >> 5, cg = j & 31;
                int gr = bm + pass * 32 + row;
                if (gr < M) {
                    f32x4 v4 = *(const f32x4*)&ls[row * 128 + cg * 4];
                    __builtin_nontemporal_store(v4, (f32x4*)&C[(long)gr * ldc + bn + cg * 4]);
                }
            }
            __syncthreads();
        }
        return;
    }

    if (C)  C  += coff;
    if (Cb) Cb += coff;
    #pragma unroll
    for (int m = 0; m < 4; m++) {
        int rb = bm + wr * 64 + m * 16 + kgrp * 4;
        #pragma unroll
        for (int n = 0; n < 4; n++) {
            int gc = bn + wc * 64 + n * 16 + lrow;
            float bvv = bias ? bias[gc] : 0.f;
            #pragma unroll
            for (int r2 = 0; r2 < 4; r2++) {
                int gr = rb + r2;
                if (gr < M) {
                    float v2 = acc[m][n][r2] * alpha + bvv;
                    if (RELU) v2 = fmaxf(v2, 0.f);
                    if (C)  C[(long)gr * ldc + gc]  = v2;
                    if (Cb) Cb[(long)gr * ldc + gc] = f2bf(v2);
                }
            }
        }
    }
}

// ---------------- HALF-tile variant: 128x64 tile, 128 threads (2 waves, 2x1) -------
// Same proven sync skeleton; 6 global_load_lds/wave/K-step -> steady vmcnt(6).
// Doubles block count for narrow-N GEMMs (PV N=128, Oproj/FFN2 N=512) that
// otherwise launch only 128 blocks on 256 CUs.
__global__ __launch_bounds__(128)
void mfma_gemm_half_kernel(const u16* __restrict__ A, int lda, long sAn, long sAh,
                           const u16* __restrict__ B, int ldb, long sBn, long sBh,
                           float* __restrict__ C, u16* __restrict__ Cb, int ldc, long sCn, long sCh,
                           const float* __restrict__ bias,
                           int M, int N, int K, int HH, float alpha)
{
    int z = blockIdx.z;
    int zn = z / HH, zh = z - zn * HH;
    A += (long)zn * sAn + (long)zh * sAh;
    B += (long)zn * sBn + (long)zh * sBh;
    long coff = (long)zn * sCn + (long)zh * sCh;

    // XCD-chunked bijective swizzle (m204)
    int nwg  = gridDim.x * gridDim.y;
    int orig = blockIdx.y * gridDim.x + blockIdx.x;
    int q = nwg >> 3, r = nwg & 7, xcd = orig & 7, rest = orig >> 3;
    int nw = (xcd < r ? xcd * (q + 1) : r * (q + 1) + (xcd - r) * q) + rest;
    int bx = nw / gridDim.y, by = nw - bx * gridDim.y;
    int bm = by * 128, bn = bx * 64;

    __shared__ u16 As[2][128 * GBK];   // 8 KB per buf
    __shared__ u16 Bs[2][64 * GBK];    // 4 KB per buf

    int tid = threadIdx.x;
    int w = tid >> 6, lane = tid & 63;          // 2 waves, stacked in M
    int lrow = lane & 15, kgrp = lane >> 4;

    auto STAGE = [&](int buf, int ks) {         // 6 global_load_lds per wave
        int k0 = ks * GBK;
        #pragma unroll
        for (int i = 0; i < 4; i++) {           // A: 512 chunks / 128 thr
            int c = tid + i * 128;
            int row = c >> 2, ko2 = (c & 3) << 3;
            int gr = bm + row; if (gr >= M) gr = M - 1;
            const u16* srcA = A + (long)gr * lda + k0 + ko2;
            u16* dstA = &As[buf][(size_t)(i * 128 + w * 64) * 8];   // wave-uniform base
            __builtin_amdgcn_global_load_lds((const __attribute__((address_space(1))) void*)srcA,
                                             (__attribute__((address_space(3))) void*)dstA, 16, 0, 0);
        }
        #pragma unroll
        for (int i = 0; i < 2; i++) {           // B: 256 chunks / 128 thr
            int c = tid + i * 128;
            int row = c >> 2, ko2 = (c & 3) << 3;
            const u16* srcB = B + (long)(bn + row) * ldb + k0 + ko2;
            u16* dstB = &Bs[buf][(size_t)(i * 128 + w * 64) * 8];
            __builtin_amdgcn_global_load_lds((const __attribute__((address_space(1))) void*)srcB,
                                             (__attribute__((address_space(3))) void*)dstB, 16, 0, 0);
        }
    };

    f32x4 acc[4][4] = {};
    int nsteps = K / GBK;

    STAGE(0, 0);     // 6 loads in flight

    for (int ks = 0; ks < nsteps; ks++) {
        int cur = ks & 1;
        if (ks + 1 < nsteps) {
            STAGE(cur ^ 1, ks + 1);                       // 6 more (12 total)
            asm volatile("s_waitcnt vmcnt(6)" ::: "memory");   // cur's 6 done
        } else {
            asm volatile("s_waitcnt vmcnt(0)" ::: "memory");
        }
        __builtin_amdgcn_sched_barrier(0);
        __builtin_amdgcn_s_barrier();
        __builtin_amdgcn_sched_barrier(0);
        bf16x8 av[4], bv[4];
        #pragma unroll
        for (int m = 0; m < 4; m++)
            av[m] = *(const bf16x8*)&As[cur][(w * 64 + m * 16 + lrow) * GBK + kgrp * 8];
        #pragma unroll
        for (int n = 0; n < 4; n++)
            bv[n] = *(const bf16x8*)&Bs[cur][(n * 16 + lrow) * GBK + kgrp * 8];
        #pragma unroll
        for (int m = 0; m < 4; m++)
            #pragma unroll
            for (int n = 0; n < 4; n++)
                acc[m][n] = __builtin_amdgcn_mfma_f32_16x16x32_bf16(av[m], bv[n], acc[m][n], 0, 0, 0);
        __builtin_amdgcn_sched_barrier(0);
        __builtin_amdgcn_s_barrier();
        __builtin_amdgcn_sched_barrier(0);
    }

    if (C)  C  += coff;
    if (Cb) Cb += coff;
    #pragma unroll
    for (int m = 0; m < 4; m++) {
        int rb = bm + w * 64 + m * 16 + kgrp * 4;
        #pragma unroll
        for (int n = 0; n < 4; n++) {
            int gc = bn + n * 16 + lrow;
            float bvv = bias ? bias[gc] : 0.f;
            #pragma unroll
            for (int r2 = 0; r2 < 4; r2++) {
                int gr = rb + r2;
                if (gr < M) {
                    float v2 = acc[m][n][r2] * alpha + bvv;
                    if (C)  C[(long)gr * ldc + gc]  = v2;
                    if (Cb) Cb[(long)gr * ldc + gc] = f2bf(v2);
                }
            }
        }
    }
}

// ---------------- causal softmax: f32 scores -> bf16 P ----------------
__global__ __launch_bounds__(256)
void softmax_causal_kernel(const float* __restrict__ scores, u16* __restrict__ pb)
{
    long row = blockIdx.x;                 // n*H*T + h*T + s
    int s = (int)(row % TLEN);
    const float* p = scores + row * TLEN;
    u16* o = pb + row * TLEN;
    int tid = threadIdx.x;
    float v0 = p[tid], v1 = p[tid + 256];
    bool m0 = (tid <= s), m1 = (tid + 256 <= s);
    __shared__ float red[256];
    float mx = fmaxf(m0 ? v0 : -INFINITY, m1 ? v1 : -INFINITY);
    red[tid] = mx; __syncthreads();
    for (int off = 128; off > 0; off >>= 1) {
        if (tid < off) red[tid] = fmaxf(red[tid], red[tid + off]);
        __syncthreads();
    }
    mx = red[0]; __syncthreads();
    float e0 = m0 ? expf(v0 - mx) : 0.f;
    float e1 = m1 ? expf(v1 - mx) : 0.f;
    red[tid] = e0 + e1; __syncthreads();
    for (int off = 128; off > 0; off >>= 1) {
        if (tid < off) red[tid] += red[tid + off];
        __syncthreads();
    }
    float inv = 1.f / red[0];
    o[tid]       = f2bf(e0 * inv);
    o[tid + 256] = f2bf(e1 * inv);
}

// ---------------- generic row reduce+normalize helper (in-kernel) ----------------
__device__ inline void ln_pass(float& v0, float& v1, const float* __restrict__ w,
                               const float* __restrict__ b, float* red, int tid)
{
    red[tid] = v0 + v1; __syncthreads();
    for (int off = 128; off > 0; off >>= 1) {
        if (tid < off) red[tid] += red[tid + off];
        __syncthreads();
    }
    float mean = red[0] * (1.f / WDIM); __syncthreads();
    float d0 = v0 - mean, d1 = v1 - mean;
    red[tid] = d0 * d0 + d1 * d1; __syncthreads();
    for (int off = 128; off > 0; off >>= 1) {
        if (tid < off) red[tid] += red[tid + off];
        __syncthreads();
    }
    float rstd = 1.f / sqrtf(red[0] * (1.f / WDIM) + 1e-5f);
    __syncthreads();
    v0 = d0 * rstd * w[tid] + b[tid];
    v1 = d1 * rstd * w[tid + 256] + b[tid + 256];
}

// ---------------- x = LayerNorm(x + t2); writes f32 x and bf16 xb ----------------
__global__ __launch_bounds__(256)
void add_ln_kernel(float* __restrict__ x, u16* __restrict__ xb,
                   const float* __restrict__ t2,
                   const float* __restrict__ w, const float* __restrict__ b)
{
    long r = blockIdx.x;
    float* xr = x + r * WDIM;
    u16* xbr = xb + r * WDIM;
    const float* tr = t2 + r * WDIM;
    int tid = threadIdx.x;
    float v0 = xr[tid] + tr[tid];
    float v1 = xr[tid + 256] + tr[tid + 256];
    __shared__ float red[256];
    ln_pass(v0, v1, w, b, red, tid);
    xr[tid] = v0;        xr[tid + 256] = v1;
    xbr[tid] = f2bf(v0); xbr[tid + 256] = f2bf(v1);
}

// ---------------- fused: x = LN2(LN1(x + t2) + cav[batch]) ----------------
__global__ __launch_bounds__(256)
void add_ln2_kernel(float* __restrict__ x, u16* __restrict__ xb,
                    const float* __restrict__ t2, const float* __restrict__ cav,
                    const float* __restrict__ w1, const float* __restrict__ b1,
                    const float* __restrict__ w2, const float* __restrict__ b2)
{
    long r = blockIdx.x;
    float* xr = x + r * WDIM;
    u16* xbr = xb + r * WDIM;
    const float* tr = t2 + r * WDIM;
    const float* cr = cav + (r / TLEN) * WDIM;   // per-batch broadcast row
    int tid = threadIdx.x;
    float v0 = xr[tid] + tr[tid];
    float v1 = xr[tid + 256] + tr[tid + 256];
    __shared__ float red[256];
    ln_pass(v0, v1, w1, b1, red, tid);
    __syncthreads();
    v0 += cr[tid]; v1 += cr[tid + 256];
    ln_pass(v0, v1, w2, b2, red, tid);
    xr[tid] = v0;        xr[tid + 256] = v1;
    xbr[tid] = f2bf(v0); xbr[tid + 256] = f2bf(v1);
}

extern "C" void kernel_launch(void* const* d_in, const int* in_sizes, int n_in,
                              void* d_out, int out_size, void* d_ws, size_t ws_size,
                              hipStream_t stream)
{
    const float* features = (const float*)d_in[0];
    const int*   captions = (const int*)  d_in[1];
    const float* emb      = (const float*)d_in[2];
    const float* pe       = (const float*)d_in[3];
    const float* vis_w    = (const float*)d_in[4];
    const float* vis_b    = (const float*)d_in[5];
    const float* sa_wq    = (const float*)d_in[6];
    const float* sa_bq    = (const float*)d_in[7];
    const float* sa_wk    = (const float*)d_in[8];
    const float* sa_bk    = (const float*)d_in[9];
    const float* sa_wv    = (const float*)d_in[10];
    const float* sa_bv    = (const float*)d_in[11];
    const float* sa_wo    = (const float*)d_in[12];
    const float* sa_bo    = (const float*)d_in[13];
    // ca_wq/bq/wk/bk (14..17) unused: len-1 memory => softmax == 1 identically
    const float* ca_wv    = (const float*)d_in[18];
    const float* ca_bv    = (const float*)d_in[19];
    const float* ca_wo    = (const float*)d_in[20];
    const float* ca_bo    = (const float*)d_in[21];
    const float* ff1_w    = (const float*)d_in[22];
    const float* ff1_b    = (const float*)d_in[23];
    const float* ff2_w    = (const float*)d_in[24];
    const float* ff2_b    = (const float*)d_in[25];
    const float* ln1_w    = (const float*)d_in[26];
    const float* ln1_b    = (const float*)d_in[27];
    const float* ln2_w    = (const float*)d_in[28];
    const float* ln2_b    = (const float*)d_in[29];
    const float* ln3_w    = (const float*)d_in[30];
    const float* ln3_b    = (const float*)d_in[31];
    const float* out_w    = (const float*)d_in[32];
    const float* out_b    = (const float*)d_in[33];

    // ---- workspace carve ----
    char* p = (char*)d_ws;
    auto alloc = [&](size_t bytes) { char* r = p; p += (bytes + 255) & ~(size_t)255; return r; };
    float* x    = (float*)alloc((size_t)NT * WDIM * 4);
    float* t2   = (float*)alloc((size_t)NT * WDIM * 4);
    float* memb = (float*)alloc((size_t)NBATCH * WDIM * 4);
    float* cav  = (float*)alloc((size_t)NLAY * NBATCH * WDIM * 4);
    // union region: scores f32 (SA phase) | yb bf16 (PV->Oproj) | hb bf16 (FFN)
    char*  reg1 = alloc((size_t)NBATCH * NHEADS * TLEN * TLEN * 4);
    float* scores = (float*)reg1;
    u16*   yb     = (u16*)reg1;
    u16*   hb     = (u16*)reg1;
    u16* xb    = (u16*)alloc((size_t)NT * WDIM * 2);
    u16* qkvb  = (u16*)alloc((size_t)NT * QKVW * 2);
    u16* vtb   = (u16*)alloc((size_t)NT * WDIM * 2);
    u16* pb    = (u16*)alloc((size_t)NBATCH * NHEADS * TLEN * TLEN * 2);
    u16* featb = (u16*)alloc((size_t)NBATCH * DFEAT * 2);
    u16* membf = (u16*)alloc((size_t)NBATCH * WDIM * 2);
    u16* cvb   = (u16*)alloc((size_t)NLAY * NBATCH * WDIM * 2);
    float* qkv_bias = (float*)alloc((size_t)NLAY * QKVW * 4);
    u16* vis_wT = (u16*)alloc((size_t)WDIM * DFEAT * 2);
    u16* qkvT   = (u16*)alloc((size_t)NLAY * QKVW * WDIM * 2);
    u16* sa_woT = (u16*)alloc((size_t)NLAY * WDIM * WDIM * 2);
    u16* ca_wvT = (u16*)alloc((size_t)NLAY * WDIM * WDIM * 2);
    u16* ca_woT = (u16*)alloc((size_t)NLAY * WDIM * WDIM * 2);
    u16* ff1T   = (u16*)alloc((size_t)NLAY * WDIM * FFDIM * 2);
    u16* ff2T   = (u16*)alloc((size_t)NLAY * FFDIM * WDIM * 2);
    u16* out_wT = (u16*)alloc((size_t)WDIM * VOCAB * 2);

    auto gemm = [&](const u16* A, int lda, long sAn, long sAh,
                    const u16* B, int ldb, long sBn, long sBh,
                    float* C, u16* Cb, int ldc, long sCn, long sCh,
                    const float* bias, long sbias, int M, int N, int K, int HH, int batch,
                    float alpha, int mode)   // 0=plain 1=relu 2=nt 3=causal
    {
        dim3 g(N / GBN, (M + GBM - 1) / GBM, batch), blk(256);
        if (mode == 2)
            mfma_gemm_kernel<0, 1, 0><<<g, blk, 0, stream>>>(A, lda, sAn, sAh, B, ldb, sBn, sBh,
                                                             C, Cb, ldc, sCn, sCh, bias, sbias, M, N, K, HH, alpha);
        else if (mode == 1)
            mfma_gemm_kernel<1, 0, 0><<<g, blk, 0, stream>>>(A, lda, sAn, sAh, B, ldb, sBn, sBh,
                                                             C, Cb, ldc, sCn, sCh, bias, sbias, M, N, K, HH, alpha);
        else if (mode == 3)
            mfma_gemm_kernel<0, 0, 1><<<g, blk, 0, stream>>>(A, lda, sAn, sAh, B, ldb, sBn, sBh,
                                                             C, Cb, ldc, sCn, sCh, bias, sbias, M, N, K, HH, alpha);
        else
            mfma_gemm_kernel<0, 0, 0><<<g, blk, 0, stream>>>(A, lda, sAn, sAh, B, ldb, sBn, sBh,
                                                             C, Cb, ldc, sCn, sCh, bias, sbias, M, N, K, HH, alpha);
    };
    // half-tile: 128x64 tile, 128 threads -- for narrow-N GEMMs (CU underfill fix)
    auto gemmh = [&](const u16* A, int lda, long sAn, long sAh,
                     const u16* B, int ldb, long sBn, long sBh,
                     float* C, u16* Cb, int ldc, long sCn, long sCh,
                     const float* bias, int M, int N, int K, int HH, int batch,
                     float alpha)
    {
        dim3 g(N / 64, (M + 127) / 128, batch), blk(128);
        mfma_gemm_half_kernel<<<g, blk, 0, stream>>>(A, lda, sAn, sAh, B, ldb, sBn, sBh,
                                                     C, Cb, ldc, sCn, sCh, bias, M, N, K, HH, alpha);
    };
    auto transposeF = [&](const float* src, int lds_, long ssn, long ssh,
                          u16* dst, int ldd, long dsn, long dsh,
                          int K, int N, int batch, int HH)
    {
        dim3 g(N / 32, K / 32, batch), blk(256);
        transpose_cvt_kernel<float><<<g, blk, 0, stream>>>(src, lds_, ssn, ssh, dst, ldd, dsn, dsh, HH);
    };
    auto transposeB = [&](const u16* src, int lds_, long ssn, long ssh,
                          u16* dst, int ldd, long dsn, long dsh,
                          int K, int N, int batch, int HH)
    {
        dim3 g(N / 32, K / 32, batch), blk(256);
        transpose_cvt_kernel<u16><<<g, blk, 0, stream>>>(src, lds_, ssn, ssh, dst, ldd, dsn, dsh, HH);
    };

    // ---- weight conversion (per call; deterministic) ----
    cvt_kernel<<<(NBATCH * DFEAT + 255) / 256, 256, 0, stream>>>(features, featb, NBATCH * DFEAT);
    concat_bias_kernel<<<(NLAY * QKVW + 255) / 256, 256, 0, stream>>>(sa_bq, sa_bk, sa_bv, qkv_bias);
    transposeF(vis_w, WDIM, 0, 0, vis_wT, DFEAT, 0, 0, DFEAT, WDIM, 1, 1);
    transposeF(sa_wq, WDIM, (long)WDIM * WDIM, 0, qkvT,                WDIM, (long)QKVW * WDIM, 0, WDIM, WDIM, NLAY, 1);
    transposeF(sa_wk, WDIM, (long)WDIM * WDIM, 0, qkvT + (long)WDIM * WDIM,     WDIM, (long)QKVW * WDIM, 0, WDIM, WDIM, NLAY, 1);
    transposeF(sa_wv, WDIM, (long)WDIM * WDIM, 0, qkvT + (long)2 * WDIM * WDIM, WDIM, (long)QKVW * WDIM, 0, WDIM, WDIM, NLAY, 1);
    transposeF(sa_wo, WDIM, (long)WDIM * WDIM, 0, sa_woT, WDIM, (long)WDIM * WDIM, 0, WDIM, WDIM, NLAY, 1);
    transposeF(ca_wv, WDIM, (long)WDIM * WDIM, 0, ca_wvT, WDIM, (long)WDIM * WDIM, 0, WDIM, WDIM, NLAY, 1);
    transposeF(ca_wo, WDIM, (long)WDIM * WDIM, 0, ca_woT, WDIM, (long)WDIM * WDIM, 0, WDIM, WDIM, NLAY, 1);
    transposeF(ff1_w, FFDIM, (long)WDIM * FFDIM, 0, ff1T, WDIM, (long)FFDIM * WDIM, 0, WDIM, FFDIM, NLAY, 1);
    transposeF(ff2_w, WDIM, (long)FFDIM * WDIM, 0, ff2T, FFDIM, (long)WDIM * FFDIM, 0, FFDIM, WDIM, NLAY, 1);
    transposeF(out_w, VOCAB, 0, 0, out_wT, WDIM, 0, 0, WDIM, VOCAB, 1, 1);

    // memory = features @ vis_w + vis_b   (8 x 512), keep f32 + bf16
    gemm(featb, DFEAT, 0, 0, vis_wT, DFEAT, 0, 0, memb, membf, WDIM, 0, 0,
         vis_b, 0, NBATCH, WDIM, DFEAT, 1, 1, 1.f, 0);
    // x = emb[captions] + pe
    embed_kernel<<<NT, 128, 0, stream>>>(captions, emb, pe, x, xb);

    // ---- cross-attention, layer-batched (len-1 memory => softmax == 1) ----
    gemm(membf, WDIM, 0, 0, ca_wvT, WDIM, (long)WDIM * WDIM, 0,
         nullptr, cvb, WDIM, (long)NBATCH * WDIM, 0,
         ca_bv, WDIM, NBATCH, WDIM, WDIM, 1, NLAY, 1.f, 0);
    gemm(cvb, WDIM, (long)NBATCH * WDIM, 0, ca_woT, WDIM, (long)WDIM * WDIM, 0,
         cav, nullptr, WDIM, (long)NBATCH * WDIM, 0,
         ca_bo, WDIM, NBATCH, WDIM, WDIM, 1, NLAY, 1.f, 0);

    const float iscale = 1.f / sqrtf((float)DHEAD);
    const long TQ = (long)TLEN * QKVW;
    const long TW = (long)TLEN * WDIM;
    const long TT = (long)TLEN * TLEN;
    for (int l = 0; l < NLAY; l++) {
        long wo  = (long)l * WDIM * WDIM;
        long bo_ = (long)l * WDIM;
        // ---- self-attention: fused QKV projection (N=1536) ----
        gemm(xb, WDIM, 0, 0, qkvT + (long)l * QKVW * WDIM, WDIM, 0, 0,
             nullptr, qkvb, QKVW, 0, 0, qkv_bias + (long)l * QKVW, 0,
             NT, QKVW, WDIM, 1, 1, 1.f, 0);
        // V^T per (n,h): qkvb[n*T+t][1024 + h*128 + d] -> vtb [n][h][d][t]
        transposeB(qkvb + 2 * WDIM, QKVW, TQ, DHEAD,
                   vtb, TLEN, (long)NHEADS * DHEAD * TLEN, (long)DHEAD * TLEN,
                   TLEN, DHEAD, NBATCH * NHEADS, NHEADS);
        // scores = (Q_h @ K_h^T) * iscale  (causal: skip fully-masked tiles)
        gemm(qkvb, QKVW, TQ, DHEAD, qkvb + WDIM, QKVW, TQ, DHEAD,
             scores, nullptr, TLEN, (long)NHEADS * TT, TT,
             nullptr, 0, TLEN, TLEN, DHEAD, NHEADS, NBATCH * NHEADS, iscale, 3);
        softmax_causal_kernel<<<NBATCH * NHEADS * TLEN, 256, 0, stream>>>(scores, pb);
        // y = P @ V_h  (half tile: N=128 -> 256 blocks)
        gemmh(pb, TLEN, (long)NHEADS * TT, TT,
              vtb, TLEN, (long)NHEADS * DHEAD * TLEN, (long)DHEAD * TLEN,
              nullptr, yb, WDIM, TW, DHEAD,
              nullptr, TLEN, DHEAD, TLEN, NHEADS, NBATCH * NHEADS, 1.f);
        // t2 = y @ wo + bo  (half tile: N=512 -> 256 blocks)
        gemmh(yb, WDIM, 0, 0, sa_woT + wo, WDIM, 0, 0, t2, nullptr, WDIM, 0, 0,
              sa_bo + bo_, NT, WDIM, WDIM, 1, 1, 1.f);
        // fused: x = LN2(LN1(x + t2) + cav[l])
        add_ln2_kernel<<<NT, 256, 0, stream>>>(x, xb, t2, cav + (long)l * NBATCH * WDIM,
                                               ln1_w + bo_, ln1_b + bo_, ln2_w + bo_, ln2_b + bo_);
        // ---- FFN ----
        gemm(xb, WDIM, 0, 0, ff1T + (long)l * FFDIM * WDIM, WDIM, 0, 0,
             nullptr, hb, FFDIM, 0, 0, ff1_b + (long)l * FFDIM, 0,
             NT, FFDIM, WDIM, 1, 1, 1.f, 1);
        // FFN2 (half tile: N=512 -> 256 blocks)
        gemmh(hb, FFDIM, 0, 0, ff2T + (long)l * WDIM * FFDIM, FFDIM, 0, 0,
              t2, nullptr, WDIM, 0, 0, ff2_b + bo_, NT, WDIM, FFDIM, 1, 1, 1.f);
        add_ln_kernel<<<NT, 256, 0, stream>>>(x, xb, t2, ln3_w + bo_, ln3_b + bo_);
    }
    // out = x @ out_w + out_b   (4096 x 32000) — coalesced non-temporal f32 stores
    gemm(xb, WDIM, 0, 0, out_wT, WDIM, 0, 0, (float*)d_out, nullptr, VOCAB, 0, 0,
         out_b, 0, NT, VOCAB, WDIM, 1, 1, 1.f, 2);
}

// Round 13
// 719.460 us; speedup vs baseline: 1.6183x; 1.0176x over previous
//
#include <hip/hip_runtime.h>
#include <math.h>

#define WDIM   512
#define TLEN   512
#define NBATCH 8
#define NHEADS 4
#define DHEAD  128
#define VOCAB  32000
#define NLAY   2
#define FFDIM  2048
#define DFEAT  1024
#define NT     (NBATCH * TLEN)   // 4096 rows
#define QKVW   (3 * WDIM)        // 1536

typedef unsigned short u16;
typedef __attribute__((ext_vector_type(8))) short bf16x8;
typedef __attribute__((ext_vector_type(4))) float f32x4;

__device__ inline u16 f2bf(float f) {
    union { float f; unsigned u; } v; v.f = f;
    unsigned r = v.u + 0x7fffu + ((v.u >> 16) & 1u);
    return (u16)(r >> 16);
}
__device__ inline u16 to_bf(float f) { return f2bf(f); }
__device__ inline u16 to_bf(u16 v)  { return v; }

// ---------------- f32 -> bf16 flat convert ----------------
__global__ __launch_bounds__(256)
void cvt_kernel(const float* __restrict__ s, u16* __restrict__ d, int n)
{
    int i = blockIdx.x * 256 + threadIdx.x;
    if (i < n) d[i] = f2bf(s[i]);
}

// ---------------- concat per-layer QKV bias: [bq;bk;bv] -> (NLAY,1536) ----------------
__global__ __launch_bounds__(256)
void concat_bias_kernel(const float* __restrict__ bq, const float* __restrict__ bk,
                        const float* __restrict__ bv, float* __restrict__ dst)
{
    int i = blockIdx.x * 256 + threadIdx.x;
    if (i >= NLAY * QKVW) return;
    int l = i / QKVW, j = i - l * QKVW;
    float v = (j < WDIM) ? bq[l * WDIM + j]
            : (j < 2 * WDIM) ? bk[l * WDIM + j - WDIM]
            : bv[l * WDIM + j - 2 * WDIM];
    dst[i] = v;
}

// ---------------- tiled transpose + convert: src (K,N) -> dst (N,K) bf16 ----------------
template<typename T>
__global__ __launch_bounds__(256)
void transpose_cvt_kernel(const T* __restrict__ src, int lds_, long ssn, long ssh,
                          u16* __restrict__ dst, int ldd, long dsn, long dsh,
                          int HH)
{
    int z = blockIdx.z;
    int zn = z / HH, zh = z - zn * HH;
    src += (long)zn * ssn + (long)zh * ssh;
    dst += (long)zn * dsn + (long)zh * dsh;
    __shared__ T tile[32][33];
    int n0 = blockIdx.x * 32, k0 = blockIdx.y * 32;
    int tx = threadIdx.x & 31, ty = threadIdx.x >> 5;  // 32 x 8
    #pragma unroll
    for (int i = 0; i < 32; i += 8)
        tile[ty + i][tx] = src[(long)(k0 + ty + i) * lds_ + n0 + tx];
    __syncthreads();
    #pragma unroll
    for (int i = 0; i < 32; i += 8)
        dst[(long)(n0 + ty + i) * ldd + k0 + tx] = to_bf(tile[tx][ty + i]);
}

// ---------------- embed + positional encoding ----------------
__global__ __launch_bounds__(128)
void embed_kernel(const int* __restrict__ captions, const float* __restrict__ emb,
                  const float* __restrict__ pe, float* __restrict__ x, u16* __restrict__ xb)
{
    int r = blockIdx.x;            // 0..NT-1
    int t = r % TLEN;
    int cap = captions[r];
    const float4* e4 = (const float4*)(emb + (long)cap * WDIM);
    const float4* p4 = (const float4*)(pe + (long)t * WDIM);
    float4 a = e4[threadIdx.x], b = p4[threadIdx.x];
    float4 o = make_float4(a.x + b.x, a.y + b.y, a.z + b.z, a.w + b.w);
    ((float4*)(x + (long)r * WDIM))[threadIdx.x] = o;
    ushort4 ob = make_ushort4(f2bf(o.x), f2bf(o.y), f2bf(o.z), f2bf(o.w));
    ((ushort4*)(xb + (long)r * WDIM))[threadIdx.x] = ob;
}

// ---------------- bf16 MFMA GEMM: 2-deep counted-vmcnt pipeline (round-8/10 proven) --
#define GBM 128
#define GBN 128
#define GBK 32

template<int RELU, int NTST, int CAUSAL>
__global__ __launch_bounds__(256)
void mfma_gemm_kernel(const u16* __restrict__ A, int lda, long sAn, long sAh,
                      const u16* __restrict__ B, int ldb, long sBn, long sBh,
                      float* __restrict__ C, u16* __restrict__ Cb, int ldc, long sCn, long sCh,
                      const float* __restrict__ bias, long sbias,
                      int M, int N, int K, int HH, float alpha)
{
    int z = blockIdx.z;
    int zn = z / HH, zh = z - zn * HH;
    A += (long)zn * sAn + (long)zh * sAh;
    B += (long)zn * sBn + (long)zh * sBh;
    long coff = (long)zn * sCn + (long)zh * sCh;
    if (bias) bias += (long)zn * sbias;

    // XCD-chunked bijective swizzle (m204)
    int nwg  = gridDim.x * gridDim.y;
    int orig = blockIdx.y * gridDim.x + blockIdx.x;
    int q = nwg >> 3, r = nwg & 7, xcd = orig & 7, rest = orig >> 3;
    int nw = (xcd < r ? xcd * (q + 1) : r * (q + 1) + (xcd - r) * q) + rest;
    int bx = nw / gridDim.y, by = nw - bx * gridDim.y;
    int bm = by * GBM, bn = bx * GBN;

    if (CAUSAL && bn >= bm + GBM) return;   // fully-masked tile (block-uniform exit)

    __shared__ u16 As[2][GBM * GBK];   // [buf][row*GBK + k], k contiguous
    __shared__ u16 Bs[2][GBN * GBK];

    int tid = threadIdx.x;
    int w = tid >> 6, lane = tid & 63;
    int wr = w >> 1, wc = w & 1;         // 2x2 wave grid, 64x64 per wave
    int lrow = lane & 15, kgrp = lane >> 4;

    int c0row = tid >> 2, c0ko = (tid & 3) << 3;
    long ldsOff = (size_t)(w * 64) * 8;

    auto STAGE = [&](int buf, int ks) {    // 4 global_load_lds per wave
        int k0 = ks * GBK;
        #pragma unroll
        for (int i = 0; i < 2; i++) {
            int row = c0row + i * 64;
            int gr = bm + row; if (gr >= M) gr = M - 1;   // clamp (ragged M=8)
            const u16* srcA = A + (long)gr * lda + k0 + c0ko;
            u16* dstA = &As[buf][ldsOff + (size_t)i * 256 * 8];
            __builtin_amdgcn_global_load_lds((const __attribute__((address_space(1))) void*)srcA,
                                             (__attribute__((address_space(3))) void*)dstA, 16, 0, 0);
            const u16* srcB = B + (long)(bn + row) * ldb + k0 + c0ko;
            u16* dstB = &Bs[buf][ldsOff + (size_t)i * 256 * 8];
            __builtin_amdgcn_global_load_lds((const __attribute__((address_space(1))) void*)srcB,
                                             (__attribute__((address_space(3))) void*)dstB, 16, 0, 0);
        }
    };

    f32x4 acc[4][4] = {};
    int nsteps = K / GBK;

    STAGE(0, 0);     // 4 loads in flight

    for (int ks = 0; ks < nsteps; ks++) {
        int cur = ks & 1;
        if (ks + 1 < nsteps) {
            STAGE(cur ^ 1, ks + 1);                       // 4 more in flight (8 total)
            asm volatile("s_waitcnt vmcnt(4)" ::: "memory");   // cur's 4 done; next's fly
        } else {
            asm volatile("s_waitcnt vmcnt(0)" ::: "memory");   // final: drain
        }
        __builtin_amdgcn_sched_barrier(0);
        __builtin_amdgcn_s_barrier();                     // all waves' cur quarters visible
        __builtin_amdgcn_sched_barrier(0);
        bf16x8 av[4], bv[4];
        #pragma unroll
        for (int m = 0; m < 4; m++)
            av[m] = *(const bf16x8*)&As[cur][(wr * 64 + m * 16 + lrow) * GBK + kgrp * 8];
        #pragma unroll
        for (int n = 0; n < 4; n++)
            bv[n] = *(const bf16x8*)&Bs[cur][(wc * 64 + n * 16 + lrow) * GBK + kgrp * 8];
        #pragma unroll
        for (int m = 0; m < 4; m++)
            #pragma unroll
            for (int n = 0; n < 4; n++)
                acc[m][n] = __builtin_amdgcn_mfma_f32_16x16x32_bf16(av[m], bv[n], acc[m][n], 0, 0, 0);
        __builtin_amdgcn_sched_barrier(0);
        __builtin_amdgcn_s_barrier();                     // reads of cur done -> safe overwrite
        __builtin_amdgcn_sched_barrier(0);
    }

    // C/D layout: col = lane&15, row = (lane>>4)*4 + reg   [m89/m91 verified]
    if (NTST) {
        __syncthreads();                  // full drain before LDS reuse
        float* ls = (float*)&As[0][0];     // 32*128 f32 = 16 KB
        C += coff;
        #pragma unroll
        for (int pass = 0; pass < 4; pass++) {
            if (wr == (pass >> 1)) {
                #pragma unroll
                for (int m2 = 0; m2 < 2; m2++) {
                    int m = (pass & 1) * 2 + m2;
                    #pragma unroll
                    for (int n = 0; n < 4; n++) {
                        int gc = wc * 64 + n * 16 + lrow;
                        float bvv = bias ? bias[bn + gc] : 0.f;
                        #pragma unroll
                        for (int r2 = 0; r2 < 4; r2++) {
                            float v2 = acc[m][n][r2] * alpha + bvv;
                            if (RELU) v2 = fmaxf(v2, 0.f);
                            ls[(m2 * 16 + kgrp * 4 + r2) * 128 + gc] = v2;
                        }
                    }
                }
            }
            __syncthreads();
            #pragma unroll
            for (int i = 0; i < 4; i++) {
                int j = tid + i * 256;            // 0..1023 f32x4
                int row = j >> 5, cg = j & 31;
                int gr = bm + pass * 32 + row;
                if (gr < M) {
                    f32x4 v4 = *(const f32x4*)&ls[row * 128 + cg * 4];
                    __builtin_nontemporal_store(v4, (f32x4*)&C[(long)gr * ldc + bn + cg * 4]);
                }
            }
            __syncthreads();
        }
        return;
    }

    if (C)  C  += coff;
    if (Cb) Cb += coff;
    #pragma unroll
    for (int m = 0; m < 4; m++) {
        int rb = bm + wr * 64 + m * 16 + kgrp * 4;
        #pragma unroll
        for (int n = 0; n < 4; n++) {
            int gc = bn + wc * 64 + n * 16 + lrow;
            float bvv = bias ? bias[gc] : 0.f;
            #pragma unroll
            for (int r2 = 0; r2 < 4; r2++) {
                int gr = rb + r2;
                if (gr < M) {
                    float v2 = acc[m][n][r2] * alpha + bvv;
                    if (RELU) v2 = fmaxf(v2, 0.f);
                    if (C)  C[(long)gr * ldc + gc]  = v2;
                    if (Cb) Cb[(long)gr * ldc + gc] = f2bf(v2);
                }
            }
        }
    }
}

// ---------------- 256x256-tile vocab GEMM: same 2-deep counted-vmcnt skeleton -------
// 512 threads = 8 waves (2M x 4N), each wave 128x64 output (acc[8][4]).
// Per K-step each wave still issues exactly 4 global_load_lds (2 A + 2 B with
// 512 threads covering 256x32 tiles) -> identical vmcnt(4) discipline.
// 32 MFMA per wave per barrier-pair (2x the 128^2 kernel) -> better amortization.
// Epilogue: 64 KB smem as [64][256] f32, 4 passes, full-line NT f32x4 stores.
__global__ __launch_bounds__(512)
void mfma_gemm256_nt_kernel(const u16* __restrict__ A, int lda,
                            const u16* __restrict__ B, int ldb,
                            float* __restrict__ C, int ldc,
                            const float* __restrict__ bias,
                            int M, int N, int K, float alpha)
{
    int nwg  = gridDim.x * gridDim.y;
    int orig = blockIdx.y * gridDim.x + blockIdx.x;
    int q = nwg >> 3, r = nwg & 7, xcd = orig & 7, rest = orig >> 3;
    int nw = (xcd < r ? xcd * (q + 1) : r * (q + 1) + (xcd - r) * q) + rest;
    int bx = nw / gridDim.y, by = nw - bx * gridDim.y;
    int bm = by * 256, bn = bx * 256;

    __shared__ u16 smem[4 * 256 * 32];     // 64 KB: As0 | As1 | Bs0 | Bs1 (16 KB each)

    int tid = threadIdx.x;
    int w = tid >> 6, lane = tid & 63;
    int wr = w >> 2, wc = w & 3;           // 2x4 wave grid; wave block 128x64
    int lrow = lane & 15, kgrp = lane >> 4;

    int c0row = tid >> 2, c0ko = (tid & 3) << 3;   // chunk c=tid: row c>>2, k-off (c&3)*8

    auto STAGE = [&](int buf, int ks) {    // 4 global_load_lds per wave (2 A + 2 B)
        int k0 = ks * GBK;
        #pragma unroll
        for (int i = 0; i < 2; i++) {
            int row = c0row + i * 128;     // chunks tid and tid+512 -> rows 0..255
            int gr = bm + row; if (gr >= M) gr = M - 1;
            const u16* srcA = A + (long)gr * lda + k0 + c0ko;
            u16* dstA = &smem[(size_t)buf * 8192 + (size_t)(i * 512 + w * 64) * 8];
            __builtin_amdgcn_global_load_lds((const __attribute__((address_space(1))) void*)srcA,
                                             (__attribute__((address_space(3))) void*)dstA, 16, 0, 0);
            const u16* srcB = B + (long)(bn + row) * ldb + k0 + c0ko;
            u16* dstB = &smem[16384 + (size_t)buf * 8192 + (size_t)(i * 512 + w * 64) * 8];
            __builtin_amdgcn_global_load_lds((const __attribute__((address_space(1))) void*)srcB,
                                             (__attribute__((address_space(3))) void*)dstB, 16, 0, 0);
        }
    };

    f32x4 acc[8][4] = {};
    int nsteps = K / GBK;

    STAGE(0, 0);

    for (int ks = 0; ks < nsteps; ks++) {
        int cur = ks & 1;
        if (ks + 1 < nsteps) {
            STAGE(cur ^ 1, ks + 1);
            asm volatile("s_waitcnt vmcnt(4)" ::: "memory");
        } else {
            asm volatile("s_waitcnt vmcnt(0)" ::: "memory");
        }
        __builtin_amdgcn_sched_barrier(0);
        __builtin_amdgcn_s_barrier();
        __builtin_amdgcn_sched_barrier(0);
        const u16* Asb = &smem[(size_t)cur * 8192];
        const u16* Bsb = &smem[16384 + (size_t)cur * 8192];
        bf16x8 av[8], bv[4];
        #pragma unroll
        for (int m = 0; m < 8; m++)
            av[m] = *(const bf16x8*)&Asb[(wr * 128 + m * 16 + lrow) * GBK + kgrp * 8];
        #pragma unroll
        for (int n = 0; n < 4; n++)
            bv[n] = *(const bf16x8*)&Bsb[(wc * 64 + n * 16 + lrow) * GBK + kgrp * 8];
        #pragma unroll
        for (int m = 0; m < 8; m++)
            #pragma unroll
            for (int n = 0; n < 4; n++)
                acc[m][n] = __builtin_amdgcn_mfma_f32_16x16x32_bf16(av[m], bv[n], acc[m][n], 0, 0, 0);
        __builtin_amdgcn_sched_barrier(0);
        __builtin_amdgcn_s_barrier();
        __builtin_amdgcn_sched_barrier(0);
    }

    __syncthreads();                       // full drain before LDS reuse
    float* ls = (float*)smem;              // 64 rows x 256 cols f32 = 64 KB
    #pragma unroll
    for (int pass = 0; pass < 4; pass++) {
        if (wr == (pass >> 1)) {
            #pragma unroll
            for (int m2 = 0; m2 < 4; m2++) {
                int m = (pass & 1) * 4 + m2;
                #pragma unroll
                for (int n = 0; n < 4; n++) {
                    int gc = wc * 64 + n * 16 + lrow;
                    float bvv = bias ? bias[bn + gc] : 0.f;
                    #pragma unroll
                    for (int r2 = 0; r2 < 4; r2++) {
                        float v2 = acc[m][n][r2] * alpha + bvv;
                        ls[(m2 * 16 + kgrp * 4 + r2) * 256 + gc] = v2;
                    }
                }
            }
        }
        __syncthreads();
        #pragma unroll
        for (int i = 0; i < 8; i++) {
            int j = tid + i * 512;         // 0..4095 f32x4
            int row = j >> 6, cg = j & 63;
            int gr = bm + pass * 64 + row;
            if (gr < M) {
                f32x4 v4 = *(const f32x4*)&ls[row * 256 + cg * 4];
                __builtin_nontemporal_store(v4, (f32x4*)&C[(long)gr * ldc + bn + cg * 4]);
            }
        }
        __syncthreads();
    }
}

// ---------------- HALF-tile variant: 128x64 tile, 128 threads (2 waves, 2x1) -------
__global__ __launch_bounds__(128)
void mfma_gemm_half_kernel(const u16* __restrict__ A, int lda, long sAn, long sAh,
                           const u16* __restrict__ B, int ldb, long sBn, long sBh,
                           float* __restrict__ C, u16* __restrict__ Cb, int ldc, long sCn, long sCh,
                           const float* __restrict__ bias,
                           int M, int N, int K, int HH, float alpha)
{
    int z = blockIdx.z;
    int zn = z / HH, zh = z - zn * HH;
    A += (long)zn * sAn + (long)zh * sAh;
    B += (long)zn * sBn + (long)zh * sBh;
    long coff = (long)zn * sCn + (long)zh * sCh;

    int nwg  = gridDim.x * gridDim.y;
    int orig = blockIdx.y * gridDim.x + blockIdx.x;
    int q = nwg >> 3, r = nwg & 7, xcd = orig & 7, rest = orig >> 3;
    int nw = (xcd < r ? xcd * (q + 1) : r * (q + 1) + (xcd - r) * q) + rest;
    int bx = nw / gridDim.y, by = nw - bx * gridDim.y;
    int bm = by * 128, bn = bx * 64;

    __shared__ u16 As[2][128 * GBK];
    __shared__ u16 Bs[2][64 * GBK];

    int tid = threadIdx.x;
    int w = tid >> 6, lane = tid & 63;
    int lrow = lane & 15, kgrp = lane >> 4;

    auto STAGE = [&](int buf, int ks) {         // 6 global_load_lds per wave
        int k0 = ks * GBK;
        #pragma unroll
        for (int i = 0; i < 4; i++) {
            int c = tid + i * 128;
            int row = c >> 2, ko2 = (c & 3) << 3;
            int gr = bm + row; if (gr >= M) gr = M - 1;
            const u16* srcA = A + (long)gr * lda + k0 + ko2;
            u16* dstA = &As[buf][(size_t)(i * 128 + w * 64) * 8];
            __builtin_amdgcn_global_load_lds((const __attribute__((address_space(1))) void*)srcA,
                                             (__attribute__((address_space(3))) void*)dstA, 16, 0, 0);
        }
        #pragma unroll
        for (int i = 0; i < 2; i++) {
            int c = tid + i * 128;
            int row = c >> 2, ko2 = (c & 3) << 3;
            const u16* srcB = B + (long)(bn + row) * ldb + k0 + ko2;
            u16* dstB = &Bs[buf][(size_t)(i * 128 + w * 64) * 8];
            __builtin_amdgcn_global_load_lds((const __attribute__((address_space(1))) void*)srcB,
                                             (__attribute__((address_space(3))) void*)dstB, 16, 0, 0);
        }
    };

    f32x4 acc[4][4] = {};
    int nsteps = K / GBK;

    STAGE(0, 0);

    for (int ks = 0; ks < nsteps; ks++) {
        int cur = ks & 1;
        if (ks + 1 < nsteps) {
            STAGE(cur ^ 1, ks + 1);
            asm volatile("s_waitcnt vmcnt(6)" ::: "memory");
        } else {
            asm volatile("s_waitcnt vmcnt(0)" ::: "memory");
        }
        __builtin_amdgcn_sched_barrier(0);
        __builtin_amdgcn_s_barrier();
        __builtin_amdgcn_sched_barrier(0);
        bf16x8 av[4], bv[4];
        #pragma unroll
        for (int m = 0; m < 4; m++)
            av[m] = *(const bf16x8*)&As[cur][(w * 64 + m * 16 + lrow) * GBK + kgrp * 8];
        #pragma unroll
        for (int n = 0; n < 4; n++)
            bv[n] = *(const bf16x8*)&Bs[cur][(n * 16 + lrow) * GBK + kgrp * 8];
        #pragma unroll
        for (int m = 0; m < 4; m++)
            #pragma unroll
            for (int n = 0; n < 4; n++)
                acc[m][n] = __builtin_amdgcn_mfma_f32_16x16x32_bf16(av[m], bv[n], acc[m][n], 0, 0, 0);
        __builtin_amdgcn_sched_barrier(0);
        __builtin_amdgcn_s_barrier();
        __builtin_amdgcn_sched_barrier(0);
    }

    if (C)  C  += coff;
    if (Cb) Cb += coff;
    #pragma unroll
    for (int m = 0; m < 4; m++) {
        int rb = bm + w * 64 + m * 16 + kgrp * 4;
        #pragma unroll
        for (int n = 0; n < 4; n++) {
            int gc = bn + n * 16 + lrow;
            float bvv = bias ? bias[gc] : 0.f;
            #pragma unroll
            for (int r2 = 0; r2 < 4; r2++) {
                int gr = rb + r2;
                if (gr < M) {
                    float v2 = acc[m][n][r2] * alpha + bvv;
                    if (C)  C[(long)gr * ldc + gc]  = v2;
                    if (Cb) Cb[(long)gr * ldc + gc] = f2bf(v2);
                }
            }
        }
    }
}

// ---------------- causal softmax: f32 scores -> bf16 P ----------------
__global__ __launch_bounds__(256)
void softmax_causal_kernel(const float* __restrict__ scores, u16* __restrict__ pb)
{
    long row = blockIdx.x;                 // n*H*T + h*T + s
    int s = (int)(row % TLEN);
    const float* p = scores + row * TLEN;
    u16* o = pb + row * TLEN;
    int tid = threadIdx.x;
    float v0 = p[tid], v1 = p[tid + 256];
    bool m0 = (tid <= s), m1 = (tid + 256 <= s);
    __shared__ float red[256];
    float mx = fmaxf(m0 ? v0 : -INFINITY, m1 ? v1 : -INFINITY);
    red[tid] = mx; __syncthreads();
    for (int off = 128; off > 0; off >>= 1) {
        if (tid < off) red[tid] = fmaxf(red[tid], red[tid + off]);
        __syncthreads();
    }
    mx = red[0]; __syncthreads();
    float e0 = m0 ? expf(v0 - mx) : 0.f;
    float e1 = m1 ? expf(v1 - mx) : 0.f;
    red[tid] = e0 + e1; __syncthreads();
    for (int off = 128; off > 0; off >>= 1) {
        if (tid < off) red[tid] += red[tid + off];
        __syncthreads();
    }
    float inv = 1.f / red[0];
    o[tid]       = f2bf(e0 * inv);
    o[tid + 256] = f2bf(e1 * inv);
}

// ---------------- generic row reduce+normalize helper (in-kernel) ----------------
__device__ inline void ln_pass(float& v0, float& v1, const float* __restrict__ w,
                               const float* __restrict__ b, float* red, int tid)
{
    red[tid] = v0 + v1; __syncthreads();
    for (int off = 128; off > 0; off >>= 1) {
        if (tid < off) red[tid] += red[tid + off];
        __syncthreads();
    }
    float mean = red[0] * (1.f / WDIM); __syncthreads();
    float d0 = v0 - mean, d1 = v1 - mean;
    red[tid] = d0 * d0 + d1 * d1; __syncthreads();
    for (int off = 128; off > 0; off >>= 1) {
        if (tid < off) red[tid] += red[tid + off];
        __syncthreads();
    }
    float rstd = 1.f / sqrtf(red[0] * (1.f / WDIM) + 1e-5f);
    __syncthreads();
    v0 = d0 * rstd * w[tid] + b[tid];
    v1 = d1 * rstd * w[tid + 256] + b[tid + 256];
}

// ---------------- x = LayerNorm(x + t2); writes f32 x and bf16 xb ----------------
__global__ __launch_bounds__(256)
void add_ln_kernel(float* __restrict__ x, u16* __restrict__ xb,
                   const float* __restrict__ t2,
                   const float* __restrict__ w, const float* __restrict__ b)
{
    long r = blockIdx.x;
    float* xr = x + r * WDIM;
    u16* xbr = xb + r * WDIM;
    const float* tr = t2 + r * WDIM;
    int tid = threadIdx.x;
    float v0 = xr[tid] + tr[tid];
    float v1 = xr[tid + 256] + tr[tid + 256];
    __shared__ float red[256];
    ln_pass(v0, v1, w, b, red, tid);
    xr[tid] = v0;        xr[tid + 256] = v1;
    xbr[tid] = f2bf(v0); xbr[tid + 256] = f2bf(v1);
}

// ---------------- fused: x = LN2(LN1(x + t2) + cav[batch]) ----------------
__global__ __launch_bounds__(256)
void add_ln2_kernel(float* __restrict__ x, u16* __restrict__ xb,
                    const float* __restrict__ t2, const float* __restrict__ cav,
                    const float* __restrict__ w1, const float* __restrict__ b1,
                    const float* __restrict__ w2, const float* __restrict__ b2)
{
    long r = blockIdx.x;
    float* xr = x + r * WDIM;
    u16* xbr = xb + r * WDIM;
    const float* tr = t2 + r * WDIM;
    const float* cr = cav + (r / TLEN) * WDIM;   // per-batch broadcast row
    int tid = threadIdx.x;
    float v0 = xr[tid] + tr[tid];
    float v1 = xr[tid + 256] + tr[tid + 256];
    __shared__ float red[256];
    ln_pass(v0, v1, w1, b1, red, tid);
    __syncthreads();
    v0 += cr[tid]; v1 += cr[tid + 256];
    ln_pass(v0, v1, w2, b2, red, tid);
    xr[tid] = v0;        xr[tid + 256] = v1;
    xbr[tid] = f2bf(v0); xbr[tid + 256] = f2bf(v1);
}

extern "C" void kernel_launch(void* const* d_in, const int* in_sizes, int n_in,
                              void* d_out, int out_size, void* d_ws, size_t ws_size,
                              hipStream_t stream)
{
    const float* features = (const float*)d_in[0];
    const int*   captions = (const int*)  d_in[1];
    const float* emb      = (const float*)d_in[2];
    const float* pe       = (const float*)d_in[3];
    const float* vis_w    = (const float*)d_in[4];
    const float* vis_b    = (const float*)d_in[5];
    const float* sa_wq    = (const float*)d_in[6];
    const float* sa_bq    = (const float*)d_in[7];
    const float* sa_wk    = (const float*)d_in[8];
    const float* sa_bk    = (const float*)d_in[9];
    const float* sa_wv    = (const float*)d_in[10];
    const float* sa_bv    = (const float*)d_in[11];
    const float* sa_wo    = (const float*)d_in[12];
    const float* sa_bo    = (const float*)d_in[13];
    // ca_wq/bq/wk/bk (14..17) unused: len-1 memory => softmax == 1 identically
    const float* ca_wv    = (const float*)d_in[18];
    const float* ca_bv    = (const float*)d_in[19];
    const float* ca_wo    = (const float*)d_in[20];
    const float* ca_bo    = (const float*)d_in[21];
    const float* ff1_w    = (const float*)d_in[22];
    const float* ff1_b    = (const float*)d_in[23];
    const float* ff2_w    = (const float*)d_in[24];
    const float* ff2_b    = (const float*)d_in[25];
    const float* ln1_w    = (const float*)d_in[26];
    const float* ln1_b    = (const float*)d_in[27];
    const float* ln2_w    = (const float*)d_in[28];
    const float* ln2_b    = (const float*)d_in[29];
    const float* ln3_w    = (const float*)d_in[30];
    const float* ln3_b    = (const float*)d_in[31];
    const float* out_w    = (const float*)d_in[32];
    const float* out_b    = (const float*)d_in[33];

    // ---- workspace carve ----
    char* p = (char*)d_ws;
    auto alloc = [&](size_t bytes) { char* r = p; p += (bytes + 255) & ~(size_t)255; return r; };
    float* x    = (float*)alloc((size_t)NT * WDIM * 4);
    float* t2   = (float*)alloc((size_t)NT * WDIM * 4);
    float* memb = (float*)alloc((size_t)NBATCH * WDIM * 4);
    float* cav  = (float*)alloc((size_t)NLAY * NBATCH * WDIM * 4);
    // union region: scores f32 (SA phase) | yb bf16 (PV->Oproj) | hb bf16 (FFN)
    char*  reg1 = alloc((size_t)NBATCH * NHEADS * TLEN * TLEN * 4);
    float* scores = (float*)reg1;
    u16*   yb     = (u16*)reg1;
    u16*   hb     = (u16*)reg1;
    u16* xb    = (u16*)alloc((size_t)NT * WDIM * 2);
    u16* qkvb  = (u16*)alloc((size_t)NT * QKVW * 2);
    u16* vtb   = (u16*)alloc((size_t)NT * WDIM * 2);
    u16* pb    = (u16*)alloc((size_t)NBATCH * NHEADS * TLEN * TLEN * 2);
    u16* featb = (u16*)alloc((size_t)NBATCH * DFEAT * 2);
    u16* membf = (u16*)alloc((size_t)NBATCH * WDIM * 2);
    u16* cvb   = (u16*)alloc((size_t)NLAY * NBATCH * WDIM * 2);
    float* qkv_bias = (float*)alloc((size_t)NLAY * QKVW * 4);
    u16* vis_wT = (u16*)alloc((size_t)WDIM * DFEAT * 2);
    u16* qkvT   = (u16*)alloc((size_t)NLAY * QKVW * WDIM * 2);
    u16* sa_woT = (u16*)alloc((size_t)NLAY * WDIM * WDIM * 2);
    u16* ca_wvT = (u16*)alloc((size_t)NLAY * WDIM * WDIM * 2);
    u16* ca_woT = (u16*)alloc((size_t)NLAY * WDIM * WDIM * 2);
    u16* ff1T   = (u16*)alloc((size_t)NLAY * WDIM * FFDIM * 2);
    u16* ff2T   = (u16*)alloc((size_t)NLAY * FFDIM * WDIM * 2);
    u16* out_wT = (u16*)alloc((size_t)WDIM * VOCAB * 2);

    auto gemm = [&](const u16* A, int lda, long sAn, long sAh,
                    const u16* B, int ldb, long sBn, long sBh,
                    float* C, u16* Cb, int ldc, long sCn, long sCh,
                    const float* bias, long sbias, int M, int N, int K, int HH, int batch,
                    float alpha, int mode)   // 0=plain 1=relu 3=causal
    {
        dim3 g(N / GBN, (M + GBM - 1) / GBM, batch), blk(256);
        if (mode == 1)
            mfma_gemm_kernel<1, 0, 0><<<g, blk, 0, stream>>>(A, lda, sAn, sAh, B, ldb, sBn, sBh,
                                                             C, Cb, ldc, sCn, sCh, bias, sbias, M, N, K, HH, alpha);
        else if (mode == 3)
            mfma_gemm_kernel<0, 0, 1><<<g, blk, 0, stream>>>(A, lda, sAn, sAh, B, ldb, sBn, sBh,
                                                             C, Cb, ldc, sCn, sCh, bias, sbias, M, N, K, HH, alpha);
        else
            mfma_gemm_kernel<0, 0, 0><<<g, blk, 0, stream>>>(A, lda, sAn, sAh, B, ldb, sBn, sBh,
                                                             C, Cb, ldc, sCn, sCh, bias, sbias, M, N, K, HH, alpha);
    };
    // half-tile: 128x64 tile, 128 threads -- for narrow-N GEMMs
    auto gemmh = [&](const u16* A, int lda, long sAn, long sAh,
                     const u16* B, int ldb, long sBn, long sBh,
                     float* C, u16* Cb, int ldc, long sCn, long sCh,
                     const float* bias, int M, int N, int K, int HH, int batch,
                     float alpha)
    {
        dim3 g(N / 64, (M + 127) / 128, batch), blk(128);
        mfma_gemm_half_kernel<<<g, blk, 0, stream>>>(A, lda, sAn, sAh, B, ldb, sBn, sBh,
                                                     C, Cb, ldc, sCn, sCh, bias, M, N, K, HH, alpha);
    };
    auto transposeF = [&](const float* src, int lds_, long ssn, long ssh,
                          u16* dst, int ldd, long dsn, long dsh,
                          int K, int N, int batch, int HH)
    {
        dim3 g(N / 32, K / 32, batch), blk(256);
        transpose_cvt_kernel<float><<<g, blk, 0, stream>>>(src, lds_, ssn, ssh, dst, ldd, dsn, dsh, HH);
    };
    auto transposeB = [&](const u16* src, int lds_, long ssn, long ssh,
                          u16* dst, int ldd, long dsn, long dsh,
                          int K, int N, int batch, int HH)
    {
        dim3 g(N / 32, K / 32, batch), blk(256);
        transpose_cvt_kernel<u16><<<g, blk, 0, stream>>>(src, lds_, ssn, ssh, dst, ldd, dsn, dsh, HH);
    };

    // ---- weight conversion (per call; deterministic) ----
    cvt_kernel<<<(NBATCH * DFEAT + 255) / 256, 256, 0, stream>>>(features, featb, NBATCH * DFEAT);
    concat_bias_kernel<<<(NLAY * QKVW + 255) / 256, 256, 0, stream>>>(sa_bq, sa_bk, sa_bv, qkv_bias);
    transposeF(vis_w, WDIM, 0, 0, vis_wT, DFEAT, 0, 0, DFEAT, WDIM, 1, 1);
    transposeF(sa_wq, WDIM, (long)WDIM * WDIM, 0, qkvT,                WDIM, (long)QKVW * WDIM, 0, WDIM, WDIM, NLAY, 1);
    transposeF(sa_wk, WDIM, (long)WDIM * WDIM, 0, qkvT + (long)WDIM * WDIM,     WDIM, (long)QKVW * WDIM, 0, WDIM, WDIM, NLAY, 1);
    transposeF(sa_wv, WDIM, (long)WDIM * WDIM, 0, qkvT + (long)2 * WDIM * WDIM, WDIM, (long)QKVW * WDIM, 0, WDIM, WDIM, NLAY, 1);
    transposeF(sa_wo, WDIM, (long)WDIM * WDIM, 0, sa_woT, WDIM, (long)WDIM * WDIM, 0, WDIM, WDIM, NLAY, 1);
    transposeF(ca_wv, WDIM, (long)WDIM * WDIM, 0, ca_wvT, WDIM, (long)WDIM * WDIM, 0, WDIM, WDIM, NLAY, 1);
    transposeF(ca_wo, WDIM, (long)WDIM * WDIM, 0, ca_woT, WDIM, (long)WDIM * WDIM, 0, WDIM, WDIM, NLAY, 1);
    transposeF(ff1_w, FFDIM, (long)WDIM * FFDIM, 0, ff1T, WDIM, (long)FFDIM * WDIM, 0, WDIM, FFDIM, NLAY, 1);
    transposeF(ff2_w, WDIM, (long)FFDIM * WDIM, 0, ff2T, FFDIM, (long)WDIM * FFDIM, 0, FFDIM, WDIM, NLAY, 1);
    transposeF(out_w, VOCAB, 0, 0, out_wT, WDIM, 0, 0, WDIM, VOCAB, 1, 1);

    // memory = features @ vis_w + vis_b   (8 x 512), keep f32 + bf16
    gemm(featb, DFEAT, 0, 0, vis_wT, DFEAT, 0, 0, memb, membf, WDIM, 0, 0,
         vis_b, 0, NBATCH, WDIM, DFEAT, 1, 1, 1.f, 0);
    // x = emb[captions] + pe
    embed_kernel<<<NT, 128, 0, stream>>>(captions, emb, pe, x, xb);

    // ---- cross-attention, layer-batched (len-1 memory => softmax == 1) ----
    gemm(membf, WDIM, 0, 0, ca_wvT, WDIM, (long)WDIM * WDIM, 0,
         nullptr, cvb, WDIM, (long)NBATCH * WDIM, 0,
         ca_bv, WDIM, NBATCH, WDIM, WDIM, 1, NLAY, 1.f, 0);
    gemm(cvb, WDIM, (long)NBATCH * WDIM, 0, ca_woT, WDIM, (long)WDIM * WDIM, 0,
         cav, nullptr, WDIM, (long)NBATCH * WDIM, 0,
         ca_bo, WDIM, NBATCH, WDIM, WDIM, 1, NLAY, 1.f, 0);

    const float iscale = 1.f / sqrtf((float)DHEAD);
    const long TQ = (long)TLEN * QKVW;
    const long TW = (long)TLEN * WDIM;
    const long TT = (long)TLEN * TLEN;
    for (int l = 0; l < NLAY; l++) {
        long wo  = (long)l * WDIM * WDIM;
        long bo_ = (long)l * WDIM;
        // ---- self-attention: fused QKV projection (N=1536) ----
        gemm(xb, WDIM, 0, 0, qkvT + (long)l * QKVW * WDIM, WDIM, 0, 0,
             nullptr, qkvb, QKVW, 0, 0, qkv_bias + (long)l * QKVW, 0,
             NT, QKVW, WDIM, 1, 1, 1.f, 0);
        // V^T per (n,h): qkvb[n*T+t][1024 + h*128 + d] -> vtb [n][h][d][t]
        transposeB(qkvb + 2 * WDIM, QKVW, TQ, DHEAD,
                   vtb, TLEN, (long)NHEADS * DHEAD * TLEN, (long)DHEAD * TLEN,
                   TLEN, DHEAD, NBATCH * NHEADS, NHEADS);
        // scores = (Q_h @ K_h^T) * iscale  (causal: skip fully-masked tiles)
        gemm(qkvb, QKVW, TQ, DHEAD, qkvb + WDIM, QKVW, TQ, DHEAD,
             scores, nullptr, TLEN, (long)NHEADS * TT, TT,
             nullptr, 0, TLEN, TLEN, DHEAD, NHEADS, NBATCH * NHEADS, iscale, 3);
        softmax_causal_kernel<<<NBATCH * NHEADS * TLEN, 256, 0, stream>>>(scores, pb);
        // y = P @ V_h  (half tile: N=128 -> 256 blocks)
        gemmh(pb, TLEN, (long)NHEADS * TT, TT,
              vtb, TLEN, (long)NHEADS * DHEAD * TLEN, (long)DHEAD * TLEN,
              nullptr, yb, WDIM, TW, DHEAD,
              nullptr, TLEN, DHEAD, TLEN, NHEADS, NBATCH * NHEADS, 1.f);
        // t2 = y @ wo + bo  (half tile: N=512 -> 256 blocks)
        gemmh(yb, WDIM, 0, 0, sa_woT + wo, WDIM, 0, 0, t2, nullptr, WDIM, 0, 0,
              sa_bo + bo_, NT, WDIM, WDIM, 1, 1, 1.f);
        // fused: x = LN2(LN1(x + t2) + cav[l])
        add_ln2_kernel<<<NT, 256, 0, stream>>>(x, xb, t2, cav + (long)l * NBATCH * WDIM,
                                               ln1_w + bo_, ln1_b + bo_, ln2_w + bo_, ln2_b + bo_);
        // ---- FFN ----
        gemm(xb, WDIM, 0, 0, ff1T + (long)l * FFDIM * WDIM, WDIM, 0, 0,
             nullptr, hb, FFDIM, 0, 0, ff1_b + (long)l * FFDIM, 0,
             NT, FFDIM, WDIM, 1, 1, 1.f, 1);
        // FFN2 (half tile: N=512 -> 256 blocks)
        gemmh(hb, FFDIM, 0, 0, ff2T + (long)l * WDIM * FFDIM, FFDIM, 0, 0,
              t2, nullptr, WDIM, 0, 0, ff2_b + bo_, NT, WDIM, FFDIM, 1, 1, 1.f);
        add_ln_kernel<<<NT, 256, 0, stream>>>(x, xb, t2, ln3_w + bo_, ln3_b + bo_);
    }
    // out = x @ out_w + out_b  (4096 x 32000) — 256x256-tile, coalesced NT stores
    {
        dim3 g(VOCAB / 256, NT / 256, 1), blk(512);
        mfma_gemm256_nt_kernel<<<g, blk, 0, stream>>>(xb, WDIM, out_wT, WDIM,
                                                      (float*)d_out, VOCAB, out_b,
                                                      NT, VOCAB, WDIM, 1.f);
    }
}